// Round 9
// baseline (168.002 us; speedup 1.0000x reference)
//
#include <hip/hip_runtime.h>
#include <cstdint>
#include <cstddef>

#define NB 4096
#define FD 256

typedef __attribute__((ext_vector_type(4))) float f32x4;
typedef __attribute__((ext_vector_type(8))) short bf16x8;

__device__ __forceinline__ ushort f2bf(float f) {
  union { float f; uint32_t u; } v; v.f = f;
  uint32_t r = v.u + 0x7fffu + ((v.u >> 16) & 1u);
  return (ushort)(r >> 16);
}
__device__ __forceinline__ float bf2f(ushort b) {
  union { uint32_t u; float f; } v; v.u = ((uint32_t)b) << 16;
  return v.f;
}

__device__ __forceinline__ void gld16(const void* g, void* l) {
  __builtin_amdgcn_global_load_lds(
      (const __attribute__((address_space(1))) char*)g,
      (__attribute__((address_space(3))) char*)l, 16, 0, 0);
}

__device__ __forceinline__ float wave_reduce_sum(float v) {
#pragma unroll
  for (int off = 32; off >= 1; off >>= 1) v += __shfl_xor(v, off);
  return v;
}

// ---------------- rownorm ---------------------------------------------------
__global__ __launch_bounds__(256) void rownorm_kernel(
    const float* __restrict__ h, const float* __restrict__ x,
    const float* __restrict__ gamma, const float* __restrict__ beta,
    ushort* __restrict__ hnb, ushort* __restrict__ xnb, float* __restrict__ diag) {
  __shared__ float rA[4], rB[4], rC[4], rD[4];
  const int r = blockIdx.x, t = threadIdx.x, wid = t >> 6, lane = t & 63;
  const size_t base = (size_t)r * FD + t;
  const float hv = h[base], xv = x[base];
  float s1 = wave_reduce_sum(hv);
  float s2 = wave_reduce_sum(hv * hv);
  float a1 = wave_reduce_sum(fabsf(xv));
  float q1 = wave_reduce_sum(xv * xv);
  if (lane == 0) { rA[wid] = s1; rB[wid] = s2; rC[wid] = a1; rD[wid] = q1; }
  __syncthreads();
  const float S1 = rA[0] + rA[1] + rA[2] + rA[3];
  const float S2 = rB[0] + rB[1] + rB[2] + rB[3];
  const float L1 = rC[0] + rC[1] + rC[2] + rC[3];
  const float Q1 = rD[0] + rD[1] + rD[2] + rD[3];
  const float mu = S1 * (1.0f / FD);
  const float var = S2 * (1.0f / FD) - mu * mu;
  const float rstd = rsqrtf(var + 1e-5f);
  const float d = fmaxf(L1, 1e-12f), dinv = 1.0f / d;
  hnb[base] = f2bf((hv - mu) * rstd * gamma[t] + beta[t]);
  xnb[base] = f2bf(xv * dinv);
  if (t == 0) diag[r] = Q1 * dinv * dinv;
}

// ---------------- weight casts ----------------------------------------------
__global__ __launch_bounds__(256) void wcast_kernel(
    const float* __restrict__ w_k, const float* __restrict__ w_q,
    const float* __restrict__ w_v,
    ushort* __restrict__ wkqb, ushort* __restrict__ wvAb,
    float* __restrict__ wvbT3) {
  const int r = blockIdx.x, t = threadIdx.x;
  wkqb[r * 256 + t] = f2bf(w_k[r * 256 + t]);
  wkqb[(256 + r) * 256 + t] = f2bf(w_q[r * 256 + t]);
  wvAb[r * 256 + t] = f2bf(w_v[(size_t)r * 259 + t]);
  if (t < 3) wvbT3[t * 256 + r] = w_v[(size_t)r * 259 + 256 + t];
}

// ---------------- bf16 transpose (64x64 tiles); z selects src/dst pair ------
__global__ __launch_bounds__(256) void transpose2_kernel(
    const ushort* __restrict__ inA, ushort* __restrict__ outA,
    const ushort* __restrict__ inB, ushort* __restrict__ outB, int R, int C) {
  __shared__ ushort tile[64][65];
  const ushort* in = blockIdx.z ? inB : inA;
  ushort* out = blockIdx.z ? outB : outA;
  const int bc = blockIdx.x * 64, br = blockIdx.y * 64;
  const int t = threadIdx.x;
#pragma unroll
  for (int i = 0; i < 16; ++i) {
    const int idx = t + 256 * i;
    const int rr = idx >> 6, cc = idx & 63;
    tile[rr][cc] = in[(size_t)(br + rr) * C + bc + cc];
  }
  __syncthreads();
#pragma unroll
  for (int i = 0; i < 16; ++i) {
    const int idx = t + 256 * i;
    const int rr = idx >> 6, cc = idx & 63;
    out[(size_t)(bc + rr) * R + br + cc] = tile[cc][rr];
  }
}

// ---------------- colsum of xn ----------------------------------------------
__global__ __launch_bounds__(256) void colsum_kernel(
    const ushort* __restrict__ xnT, float* __restrict__ s) {
  __shared__ float red[4];
  const int f = blockIdx.x, t = threadIdx.x, wid = t >> 6, lane = t & 63;
  float a = 0.f;
#pragma unroll
  for (int i = 0; i < 16; ++i) a += bf2f(xnT[(size_t)f * NB + t + 256 * i]);
  a = wave_reduce_sum(a);
  if (lane == 0) red[wid] = a;
  __syncthreads();
  if (t == 0) s[f] = red[0] + red[1] + red[2] + red[3];
}

// ---------------- Gram split-K reduce: [16][256][512] -> G | M2T ------------
__global__ __launch_bounds__(256) void reduce16g_kernel(
    const float* __restrict__ in, ushort* __restrict__ t23B,
    ushort* __restrict__ M2T) {
  const int idx = blockIdx.x * 256 + threadIdx.x;   // over 256*512
  const int i = idx >> 9, j = idx & 511;
  float a = 0.f;
#pragma unroll
  for (int z = 0; z < 16; ++z) a += in[(size_t)z * (256 * 512) + idx];
  if (j < 256) t23B[i * 256 + j] = f2bf(a);
  else M2T[i * 256 + (j - 256)] = f2bf(a);
}

// ---------------- fused row softmax + transpose ------------------------------
// 256 blocks x 16-row stripes, 256 threads (16 threads per row).
// Pass1 max, pass2 sumexp, pass3 normalize -> write P and PT (LDS 16x64 tile).
__global__ __launch_bounds__(256) void softmax_t_kernel(
    const ushort* __restrict__ S, ushort* __restrict__ P,
    ushort* __restrict__ PT) {
  __shared__ ushort tile[16][66];
  const int t = threadIdx.x;
  const int rl = t >> 4, sub = t & 15;
  const int r0 = blockIdx.x * 16;
  const ushort* Srow = S + (size_t)(r0 + rl) * NB;
  ushort* Prow = P + (size_t)(r0 + rl) * NB;

  float m = -1e30f;
  for (int c = sub * 8; c < NB; c += 128) {
    const uint4 cc = *(const uint4*)(Srow + c);
    const uint32_t w4[4] = {cc.x, cc.y, cc.z, cc.w};
#pragma unroll
    for (int j = 0; j < 4; ++j) {
      m = fmaxf(m, bf2f((ushort)(w4[j] & 0xffffu)));
      m = fmaxf(m, bf2f((ushort)(w4[j] >> 16)));
    }
  }
  m = fmaxf(m, __shfl_xor(m, 1));
  m = fmaxf(m, __shfl_xor(m, 2));
  m = fmaxf(m, __shfl_xor(m, 4));
  m = fmaxf(m, __shfl_xor(m, 8));

  float s = 0.f;
  for (int c = sub * 8; c < NB; c += 128) {
    const uint4 cc = *(const uint4*)(Srow + c);
    const uint32_t w4[4] = {cc.x, cc.y, cc.z, cc.w};
#pragma unroll
    for (int j = 0; j < 4; ++j) {
      s += __expf(bf2f((ushort)(w4[j] & 0xffffu)) - m);
      s += __expf(bf2f((ushort)(w4[j] >> 16)) - m);
    }
  }
  s += __shfl_xor(s, 1);
  s += __shfl_xor(s, 2);
  s += __shfl_xor(s, 4);
  s += __shfl_xor(s, 8);
  const float pinv = 1.f / s;

  const int jj = t >> 2;           // 0..63 (PT row within col-tile)
  const int ii = (t & 3) * 4;      // 0..12 (PT col quad within stripe)
  for (int ct = 0; ct < 64; ++ct) {
    const int c = ct * 64 + sub * 4;
    const ushort4 sv = *(const ushort4*)(Srow + c);
    ushort4 o;
    o.x = f2bf(__expf(bf2f(sv.x) - m) * pinv);
    o.y = f2bf(__expf(bf2f(sv.y) - m) * pinv);
    o.z = f2bf(__expf(bf2f(sv.z) - m) * pinv);
    o.w = f2bf(__expf(bf2f(sv.w) - m) * pinv);
    *(ushort4*)(Prow + c) = o;
    *(ushort4*)(&tile[rl][sub * 4]) = o;
    __syncthreads();
    ushort4 ot;
    ot.x = tile[ii + 0][jj];
    ot.y = tile[ii + 1][jj];
    ot.z = tile[ii + 2][jj];
    ot.w = tile[ii + 3][jj];
    *(ushort4*)(PT + (size_t)(ct * 64 + jj) * NB + r0 + ii) = ot;
    __syncthreads();
  }
}

// ---------------- mega combine: both outputs --------------------------------
__global__ __launch_bounds__(256) void megacombine_kernel(
    const ushort* __restrict__ px, const ushort* __restrict__ ph,
    const float* __restrict__ t23, const ushort* __restrict__ xnb,
    const float* __restrict__ sv, const float* __restrict__ diag,
    const float* __restrict__ x, const float* __restrict__ h,
    const float* __restrict__ wvbT3, const float* __restrict__ mix,
    float* __restrict__ out_x, float* __restrict__ out_h) {
  __shared__ float rA[4], rB[4];
  const size_t NF = (size_t)NB * FD;
  const int i = blockIdx.x, f = threadIdx.x, wid = f >> 6, lane = f & 63;
  const float e0x = __expf(mix[0]), e1x = __expf(mix[2]);
  const float mAx = e0x / (e0x + e1x), mBx = e1x / (e0x + e1x);
  const float e0h = __expf(mix[1]), e1h = __expf(mix[3]);
  const float mAh = e0h / (e0h + e1h), mBh = e1h / (e0h + e1h);

  const size_t rowoff = (size_t)i * FD + f;
  float ax = 0.f, ah = 0.f;
#pragma unroll
  for (int z = 0; z < 8; ++z) {
    ax += bf2f(px[(size_t)z * NF + rowoff]);
    ah += bf2f(ph[(size_t)z * NF + rowoff]);
  }
  const float t2v = t23[(size_t)i * 512 + f];
  const float t3v = t23[(size_t)i * 512 + 256 + f];
  const float xv = bf2f(xnb[rowoff]);

  float rs = wave_reduce_sum(xv * sv[f]);
  float rq = wave_reduce_sum(xv * t2v);
  if (lane == 0) { rA[wid] = rs; rB[wid] = rq; }
  __syncthreads();
  rs = rA[0] + rA[1] + rA[2] + rA[3];
  rq = rB[0] + rB[1] + rB[2] + rB[3];
  const float mean = rs * (1.0f / NB);
  const float var = (rq - (float)NB * mean * mean) * (1.0f / (NB - 1));
  const float sd = sqrtf(fmaxf(var, 0.f));
  const float dg = diag[i];
  const float statsterm = dg * wvbT3[f] + rs * wvbT3[256 + f] + sd * wvbT3[512 + f];

  out_x[rowoff] = mBx * ax + mAx * t2v + x[rowoff];
  const float pre = mBh * ah + mAh * t3v + statsterm;
  out_h[rowoff] = ((pre > 0.f) ? pre : expm1f(pre)) + h[rowoff];
}

// ---------------- batched 64x64 NT GEMM (3 slices, runtime descriptors) -----
struct GDesc {
  const ushort* A; const ushort* B; void* C;
  int lda, ldb, ldc, K, gx, gy, epi;   // epi: 1 bf16 store, 5 splitK fp32
  float alpha; long pstride; int nb;   // nb = total blocks in slice
};

__global__ __launch_bounds__(256) void gemm_batch3(
    GDesc d0, GDesc d1, GDesc d2, int ntot) {
  int flat = blockIdx.x;
  flat = (flat & 7) * (ntot >> 3) + (flat >> 3);   // XCD chunk swizzle (ntot%8==0)
  GDesc d; int l;
  if (flat < d0.nb) { d = d0; l = flat; }
  else if (flat < d0.nb + d1.nb) { d = d1; l = flat - d0.nb; }
  else { d = d2; l = flat - d0.nb - d1.nb; }
  const int bx = l % d.gx;
  const int rest = l / d.gx;
  const int by = rest % d.gy, bz = rest / d.gy;

  __shared__ __align__(16) ushort At[2][64][32];
  __shared__ __align__(16) ushort Bt[2][64][32];
  const int tid = threadIdx.x;
  const int wave = tid >> 6, lane = tid & 63;
  const int wr = wave >> 1, wc = wave & 1;
  const int bi = by * 64, bj = bx * 64;
  const int fr = lane & 15, fq = lane >> 4;
  const int sub = lane >> 2, q = lane & 3;

  f32x4 acc[2][2];
#pragma unroll
  for (int m = 0; m < 2; ++m)
#pragma unroll
    for (int n = 0; n < 2; ++n) acc[m][n] = (f32x4){0.f, 0.f, 0.f, 0.f};

  const int kbase = bz * d.K;
  const int kend = kbase + d.K;

  auto stage = [&](int bufi, int k0) {
    {
      const int row = wave * 16 + sub;
      const int qs = q ^ (row & 3);
      gld16(d.A + (size_t)(bi + row) * d.lda + k0 + qs * 8, &At[bufi][wave * 16][0]);
    }
    {
      const int row = wave * 16 + sub;
      const int qs = q ^ (row & 3);
      gld16(d.B + (size_t)(bj + row) * d.ldb + k0 + qs * 8, &Bt[bufi][wave * 16][0]);
    }
  };

  stage(0, kbase);
  __syncthreads();

  int cur = 0;
  for (int k0 = kbase; k0 < kend; k0 += 32) {
    if (k0 + 32 < kend) stage(cur ^ 1, k0 + 32);
    bf16x8 a[2], b[2];
#pragma unroll
    for (int m = 0; m < 2; ++m) {
      const int row = wr * 32 + m * 16 + fr;
      a[m] = *(const bf16x8*)((const char*)&At[cur][row][0] + ((fq ^ (row & 3)) * 16));
    }
#pragma unroll
    for (int n = 0; n < 2; ++n) {
      const int row = wc * 32 + n * 16 + fr;
      b[n] = *(const bf16x8*)((const char*)&Bt[cur][row][0] + ((fq ^ (row & 3)) * 16));
    }
#pragma unroll
    for (int m = 0; m < 2; ++m)
#pragma unroll
      for (int n = 0; n < 2; ++n)
        acc[m][n] = __builtin_amdgcn_mfma_f32_16x16x32_bf16(a[m], b[n], acc[m][n], 0, 0, 0);
    __syncthreads();
    cur ^= 1;
  }

#pragma unroll
  for (int m = 0; m < 2; ++m)
#pragma unroll
    for (int n = 0; n < 2; ++n)
#pragma unroll
      for (int r = 0; r < 4; ++r) {
        const int row = bi + wr * 32 + m * 16 + fq * 4 + r;
        const int col = bj + wc * 32 + n * 16 + fr;
        const size_t ci = (size_t)row * d.ldc + col;
        const float v = acc[m][n][r];
        if (d.epi == 1) ((ushort*)d.C)[ci] = f2bf(v * d.alpha);
        else ((float*)d.C)[(size_t)bz * d.pstride + ci] = v;
      }
}

// ---------------- NT bf16 MFMA GEMM, 2-phase dbuf + XCD swizzle -------------
// EPI: 0 fp32*alpha | 1 bf16*alpha | 5 splitK fp32 partial | 6 splitK bf16
template <int BM, int BN, int EPI>
__global__ __launch_bounds__(256) void gemm_nt(
    const ushort* __restrict__ A, int lda,
    const ushort* __restrict__ B, int ldb,
    void* __restrict__ Cp, int ldc, int K, float alpha,
    size_t pstride) {
  constexpr int WAVES_N = (BM <= 32) ? 4 : 2;
  constexpr int WAVES_M = 4 / WAVES_N;
  constexpr int WM = BM / WAVES_M, WN = BN / WAVES_N;
  constexpr int MR = WM / 16, NR = WN / 16;
  __shared__ __align__(16) ushort At[2][BM][32];
  __shared__ __align__(16) ushort Bt[2][BN][32];
  const int tid = threadIdx.x;
  const int wave = tid >> 6, lane = tid & 63;
  const int wr = wave / WAVES_N, wc = wave % WAVES_N;

  const int gx = gridDim.x, gy = gridDim.y;
  const int nwg = gx * gy * gridDim.z;
  int flat = blockIdx.x + gx * (blockIdx.y + gy * blockIdx.z);
  if ((nwg & 7) == 0) flat = (flat & 7) * (nwg >> 3) + (flat >> 3);
  const int bx = flat % gx, by = (flat / gx) % gy, bz = flat / (gx * gy);

  const int bi = by * BM, bj = bx * BN;
  const int fr = lane & 15, fq = lane >> 4;
  const int sub = lane >> 2, q = lane & 3;

  f32x4 acc[MR][NR];
#pragma unroll
  for (int m = 0; m < MR; ++m)
#pragma unroll
    for (int n = 0; n < NR; ++n) acc[m][n] = (f32x4){0.f, 0.f, 0.f, 0.f};

  const int kbase = (EPI >= 5) ? bz * K : 0;
  const int kend = kbase + K;

  auto stage = [&](int bufi, int k0) {
    for (int c = wave; c < BM / 16; c += 4) {
      const int row = c * 16 + sub;
      const int qs = q ^ (row & 3);
      gld16(A + (size_t)(bi + row) * lda + k0 + qs * 8, &At[bufi][c * 16][0]);
    }
    for (int c = wave; c < BN / 16; c += 4) {
      const int row = c * 16 + sub;
      const int qs = q ^ (row & 3);
      gld16(B + (size_t)(bj + row) * ldb + k0 + qs * 8, &Bt[bufi][c * 16][0]);
    }
  };

  stage(0, kbase);
  __syncthreads();

  int cur = 0;
  for (int k0 = kbase; k0 < kend; k0 += 32) {
    if (k0 + 32 < kend) stage(cur ^ 1, k0 + 32);
    bf16x8 a[MR], b[NR];
#pragma unroll
    for (int m = 0; m < MR; ++m) {
      const int row = wr * WM + m * 16 + fr;
      a[m] = *(const bf16x8*)((const char*)&At[cur][row][0] + ((fq ^ (row & 3)) * 16));
    }
#pragma unroll
    for (int n = 0; n < NR; ++n) {
      const int row = wc * WN + n * 16 + fr;
      b[n] = *(const bf16x8*)((const char*)&Bt[cur][row][0] + ((fq ^ (row & 3)) * 16));
    }
#pragma unroll
    for (int m = 0; m < MR; ++m)
#pragma unroll
      for (int n = 0; n < NR; ++n)
        acc[m][n] = __builtin_amdgcn_mfma_f32_16x16x32_bf16(a[m], b[n], acc[m][n], 0, 0, 0);
    __syncthreads();
    cur ^= 1;
  }

#pragma unroll
  for (int m = 0; m < MR; ++m)
#pragma unroll
    for (int n = 0; n < NR; ++n)
#pragma unroll
      for (int r = 0; r < 4; ++r) {
        const int row = bi + wr * WM + m * 16 + fq * 4 + r;
        const int col = bj + wc * WN + n * 16 + fr;
        const size_t ci = (size_t)row * ldc + col;
        const float v = acc[m][n][r];
        if (EPI == 0) ((float*)Cp)[ci] = v * alpha;
        else if (EPI == 1) ((ushort*)Cp)[ci] = f2bf(v * alpha);
        else if (EPI == 5) ((float*)Cp)[(size_t)bz * pstride + ci] = v;
        else if (EPI == 6) ((ushort*)Cp)[(size_t)bz * pstride + ci] = f2bf(v);
      }
}

// ---------------------------------------------------------------------------
extern "C" void kernel_launch(void* const* d_in, const int* in_sizes, int n_in,
                              void* d_out, int out_size, void* d_ws, size_t ws_size,
                              hipStream_t stream) {
  const float* h      = (const float*)d_in[0];
  const float* x      = (const float*)d_in[1];
  const float* w_k    = (const float*)d_in[2];
  const float* w_q    = (const float*)d_in[3];
  const float* w_v    = (const float*)d_in[4];
  const float* mixing = (const float*)d_in[5];
  const float* gamma  = (const float*)d_in[6];
  const float* beta   = (const float*)d_in[7];

  float* out_h = (float*)d_out;
  float* out_x = out_h + (size_t)NB * FD;

  char* w = (char*)d_ws;
  ushort* S     = (ushort*)(w + 0);           // 32MB bf16 scores
  ushort* P     = (ushort*)(w + 33554432);    // 32MB
  ushort* PT    = (ushort*)(w + 67108864);    // 32MB
  ushort* hnb   = (ushort*)(w + 100663296);   // 2MB
  ushort* xnb   = (ushort*)(w + 102760448);   // 2MB
  ushort* xnbT  = (ushort*)(w + 104857600);   // 2MB  [256][NB] (stack base)
  ushort* hnbT  = (ushort*)(w + 106954752);   // 2MB  [256][NB] (stack rows 256-511)
  ushort* kq    = (ushort*)(w + 109051904);   // 4MB  [NB][512]
  ushort* hvT   = (ushort*)(w + 113246208);   // 2MB  [256][NB]
  float*  t23   = (float*)(w + 115343360);    // 8MB  [NB][512]
  ushort* t23B  = (ushort*)(w + 123731968);   // 256KB [512][256] (G | Bv)
  ushort* M2T   = (ushort*)(w + 123994112);   // 128KB
  ushort* wkqb  = (ushort*)(w + 124125184);   // 256KB [512][256]
  ushort* wvAb  = (ushort*)(w + 124387328);   // 128KB
  float*  wvbT3 = (float*)(w + 124518400);    // 3KB
  float*  diag  = (float*)(w + 124521472);    // 16KB
  float*  sv    = (float*)(w + 124537856);    // 1KB
  // aliases (disjoint lifetimes):
  float*  Gramp = (float*)(w + 67108864);     // 8MB in PT region (dead before PT)
  ushort* px    = (ushort*)(w + 0);           // 16MB in S region (S dead after softmax)
  ushort* ph    = (ushort*)(w + 16777216);    // 16MB

  rownorm_kernel<<<NB, 256, 0, stream>>>(h, x, gamma, beta, hnb, xnb, diag);
  wcast_kernel<<<FD, 256, 0, stream>>>(w_k, w_q, w_v, wkqb, wvAb, wvbT3);
  transpose2_kernel<<<dim3(FD / 64, NB / 64, 2), 256, 0, stream>>>(
      xnb, xnbT, hnb, hnbT, NB, FD);
  colsum_kernel<<<FD, 256, 0, stream>>>(xnbT, sv);

  // batched: kq = hn @ [w_k;w_q]^T | Gram stacked (split-K 16) | hvT = w_vA @ hn^T
  {
    GDesc dkq = {hnb, wkqb, kq, FD, FD, 512, FD, 8, 64, 1, 1.f, 0, 512};
    GDesc dgr = {xnbT, xnbT, Gramp, NB, NB, 512, NB / 16, 8, 4, 5, 1.f,
                 (long)(256 * 512), 512};
    GDesc dhv = {wvAb, hnb, hvT, FD, FD, NB, FD, 64, 4, 1, 1.f, 0, 256};
    gemm_batch3<<<1280, 256, 0, stream>>>(dkq, dgr, dhv, 1280);
  }
  reduce16g_kernel<<<256 * 512 / 256, 256, 0, stream>>>(Gramp, t23B, M2T);

  // Bv = w_vA @ M2 (via M2T)
  gemm_nt<64, 64, 1><<<dim3(4, 4), 256, 0, stream>>>(
      wvAb, FD, M2T, FD, t23B + 256 * 256, FD, FD, 1.f, 0);

  // t23 = xn @ [G; Bv]^T -> [NB, 512] fp32
  gemm_nt<64, 64, 0><<<dim3(512 / 64, NB / 64), 256, 0, stream>>>(
      xnb, FD, t23B, FD, t23, 512, FD, 1.f, 0);

  // S = bf16((k @ q^T) / 16)
  gemm_nt<128, 128, 1><<<dim3(NB / 128, NB / 128), 256, 0, stream>>>(
      kq, 512, kq + 256, 512, S, NB, FD, 0.0625f, 0);

  // fused softmax + transpose: S -> P, PT
  softmax_t_kernel<<<NB / 16, 256, 0, stream>>>(S, P, PT);

  // aggregation partials: 128x128 tiles, split-K 8
  gemm_nt<128, 128, 6><<<dim3(FD / 128, NB / 128, 8), 256, 0, stream>>>(
      P, NB, xnbT, NB, px, FD, NB / 8, 1.f, (size_t)NB * FD);
  gemm_nt<128, 128, 6><<<dim3(FD / 128, NB / 128, 8), 256, 0, stream>>>(
      PT, NB, hvT, NB, ph, FD, NB / 8, 1.f, (size_t)NB * FD);

  // mega combine -> out_x, out_h
  megacombine_kernel<<<NB, 256, 0, stream>>>(
      px, ph, t23, xnb, sv, diag, x, h, wvbT3, mixing, out_x, out_h);
}

// Round 10
// 134.019 us; speedup vs baseline: 1.2536x; 1.2536x over previous
//
#include <hip/hip_runtime.h>
#include <cstdint>
#include <cstddef>

#define NB 4096
#define FD 256

typedef __attribute__((ext_vector_type(4))) float f32x4;
typedef __attribute__((ext_vector_type(8))) short bf16x8;

__device__ __forceinline__ ushort f2bf(float f) {
  union { float f; uint32_t u; } v; v.f = f;
  uint32_t r = v.u + 0x7fffu + ((v.u >> 16) & 1u);
  return (ushort)(r >> 16);
}
__device__ __forceinline__ float bf2f(ushort b) {
  union { uint32_t u; float f; } v; v.u = ((uint32_t)b) << 16;
  return v.f;
}

__device__ __forceinline__ void gld16(const void* g, void* l) {
  __builtin_amdgcn_global_load_lds(
      (const __attribute__((address_space(1))) char*)g,
      (__attribute__((address_space(3))) char*)l, 16, 0, 0);
}

__device__ __forceinline__ float wave_reduce_sum(float v) {
#pragma unroll
  for (int off = 32; off >= 1; off >>= 1) v += __shfl_xor(v, off);
  return v;
}
__device__ __forceinline__ float wave_reduce_max(float v) {
#pragma unroll
  for (int off = 32; off >= 1; off >>= 1) v = fmaxf(v, __shfl_xor(v, off));
  return v;
}

// ---------------- rownorm ---------------------------------------------------
__global__ __launch_bounds__(256) void rownorm_kernel(
    const float* __restrict__ h, const float* __restrict__ x,
    const float* __restrict__ gamma, const float* __restrict__ beta,
    ushort* __restrict__ hnb, ushort* __restrict__ xnb, float* __restrict__ diag) {
  __shared__ float rA[4], rB[4], rC[4], rD[4];
  const int r = blockIdx.x, t = threadIdx.x, wid = t >> 6, lane = t & 63;
  const size_t base = (size_t)r * FD + t;
  const float hv = h[base], xv = x[base];
  float s1 = wave_reduce_sum(hv);
  float s2 = wave_reduce_sum(hv * hv);
  float a1 = wave_reduce_sum(fabsf(xv));
  float q1 = wave_reduce_sum(xv * xv);
  if (lane == 0) { rA[wid] = s1; rB[wid] = s2; rC[wid] = a1; rD[wid] = q1; }
  __syncthreads();
  const float S1 = rA[0] + rA[1] + rA[2] + rA[3];
  const float S2 = rB[0] + rB[1] + rB[2] + rB[3];
  const float L1 = rC[0] + rC[1] + rC[2] + rC[3];
  const float Q1 = rD[0] + rD[1] + rD[2] + rD[3];
  const float mu = S1 * (1.0f / FD);
  const float var = S2 * (1.0f / FD) - mu * mu;
  const float rstd = rsqrtf(var + 1e-5f);
  const float d = fmaxf(L1, 1e-12f), dinv = 1.0f / d;
  hnb[base] = f2bf((hv - mu) * rstd * gamma[t] + beta[t]);
  xnb[base] = f2bf(xv * dinv);
  if (t == 0) diag[r] = Q1 * dinv * dinv;
}

// ---------------- weight casts ----------------------------------------------
__global__ __launch_bounds__(256) void wcast_kernel(
    const float* __restrict__ w_k, const float* __restrict__ w_q,
    const float* __restrict__ w_v,
    ushort* __restrict__ wkqb, ushort* __restrict__ wvAb,
    float* __restrict__ wvbT3) {
  const int r = blockIdx.x, t = threadIdx.x;
  wkqb[r * 256 + t] = f2bf(w_k[r * 256 + t]);
  wkqb[(256 + r) * 256 + t] = f2bf(w_q[r * 256 + t]);
  wvAb[r * 256 + t] = f2bf(w_v[(size_t)r * 259 + t]);
  if (t < 3) wvbT3[t * 256 + r] = w_v[(size_t)r * 259 + 256 + t];
}

// ---------------- bf16 transpose (64x64 tiles); z selects src/dst pair ------
__global__ __launch_bounds__(256) void transpose2_kernel(
    const ushort* __restrict__ inA, ushort* __restrict__ outA,
    const ushort* __restrict__ inB, ushort* __restrict__ outB, int R, int C) {
  __shared__ ushort tile[64][65];
  const ushort* in = blockIdx.z ? inB : inA;
  ushort* out = blockIdx.z ? outB : outA;
  const int bc = blockIdx.x * 64, br = blockIdx.y * 64;
  const int t = threadIdx.x;
#pragma unroll
  for (int i = 0; i < 16; ++i) {
    const int idx = t + 256 * i;
    const int rr = idx >> 6, cc = idx & 63;
    tile[rr][cc] = in[(size_t)(br + rr) * C + bc + cc];
  }
  __syncthreads();
#pragma unroll
  for (int i = 0; i < 16; ++i) {
    const int idx = t + 256 * i;
    const int rr = idx >> 6, cc = idx & 63;
    out[(size_t)(bc + rr) * R + br + cc] = tile[cc][rr];
  }
}

__global__ __launch_bounds__(256) void transpose_kernel(
    const ushort* __restrict__ in, ushort* __restrict__ out, int R, int C) {
  __shared__ ushort tile[64][65];
  const int bc = blockIdx.x * 64, br = blockIdx.y * 64;
  const int t = threadIdx.x;
#pragma unroll
  for (int i = 0; i < 16; ++i) {
    const int idx = t + 256 * i;
    const int rr = idx >> 6, cc = idx & 63;
    tile[rr][cc] = in[(size_t)(br + rr) * C + bc + cc];
  }
  __syncthreads();
#pragma unroll
  for (int i = 0; i < 16; ++i) {
    const int idx = t + 256 * i;
    const int rr = idx >> 6, cc = idx & 63;
    out[(size_t)(bc + rr) * R + br + cc] = tile[cc][rr];
  }
}

// ---------------- colsum of xn ----------------------------------------------
__global__ __launch_bounds__(256) void colsum_kernel(
    const ushort* __restrict__ xnT, float* __restrict__ s) {
  __shared__ float red[4];
  const int f = blockIdx.x, t = threadIdx.x, wid = t >> 6, lane = t & 63;
  float a = 0.f;
#pragma unroll
  for (int i = 0; i < 16; ++i) a += bf2f(xnT[(size_t)f * NB + t + 256 * i]);
  a = wave_reduce_sum(a);
  if (lane == 0) red[wid] = a;
  __syncthreads();
  if (t == 0) s[f] = red[0] + red[1] + red[2] + red[3];
}

// ---------------- Gram split-K reduce: [16][256][512] -> G | M2T ------------
__global__ __launch_bounds__(256) void reduce16g_kernel(
    const float* __restrict__ in, ushort* __restrict__ t23B,
    ushort* __restrict__ M2T) {
  const int idx = blockIdx.x * 256 + threadIdx.x;   // over 256*512
  const int i = idx >> 9, j = idx & 511;
  float a = 0.f;
#pragma unroll
  for (int z = 0; z < 16; ++z) a += in[(size_t)z * (256 * 512) + idx];
  if (j < 256) t23B[i * 256 + j] = f2bf(a);
  else M2T[i * 256 + (j - 256)] = f2bf(a);
}

// ---------------- row softmax: S bf16 -> P bf16 -----------------------------
__global__ __launch_bounds__(256) void softmax_kernel(
    const ushort* __restrict__ S, ushort* __restrict__ P) {
  __shared__ float red[4];
  const int r = blockIdx.x, t = threadIdx.x, wid = t >> 6, lane = t & 63;
  const uint4* Sr = (const uint4*)(S + (size_t)r * NB);
  float v[16];
  float lmax = -1e30f;
#pragma unroll
  for (int i = 0; i < 2; ++i) {
    const uint4 c = Sr[t + 256 * i];
    const uint32_t w4[4] = {c.x, c.y, c.z, c.w};
#pragma unroll
    for (int j = 0; j < 4; ++j) {
      v[i * 8 + j * 2]     = bf2f((ushort)(w4[j] & 0xffffu));
      v[i * 8 + j * 2 + 1] = bf2f((ushort)(w4[j] >> 16));
    }
  }
#pragma unroll
  for (int u = 0; u < 16; ++u) lmax = fmaxf(lmax, v[u]);
  lmax = wave_reduce_max(lmax);
  if (lane == 0) red[wid] = lmax;
  __syncthreads();
  const float gmax = fmaxf(fmaxf(red[0], red[1]), fmaxf(red[2], red[3]));
  __syncthreads();
  float lsum = 0.f;
#pragma unroll
  for (int u = 0; u < 16; ++u) { v[u] = __expf(v[u] - gmax); lsum += v[u]; }
  lsum = wave_reduce_sum(lsum);
  if (lane == 0) red[wid] = lsum;
  __syncthreads();
  const float pinv = 1.f / (red[0] + red[1] + red[2] + red[3]);
  uint4* Pr = (uint4*)(P + (size_t)r * NB);
#pragma unroll
  for (int i = 0; i < 2; ++i) {
    uint4 o;
    o.x = (uint32_t)f2bf(v[i*8+0] * pinv) | ((uint32_t)f2bf(v[i*8+1] * pinv) << 16);
    o.y = (uint32_t)f2bf(v[i*8+2] * pinv) | ((uint32_t)f2bf(v[i*8+3] * pinv) << 16);
    o.z = (uint32_t)f2bf(v[i*8+4] * pinv) | ((uint32_t)f2bf(v[i*8+5] * pinv) << 16);
    o.w = (uint32_t)f2bf(v[i*8+6] * pinv) | ((uint32_t)f2bf(v[i*8+7] * pinv) << 16);
    Pr[t + 256 * i] = o;
  }
}

// ---------------- mega combine: both outputs --------------------------------
__global__ __launch_bounds__(256) void megacombine_kernel(
    const ushort* __restrict__ px, const ushort* __restrict__ ph,
    const float* __restrict__ t23, const ushort* __restrict__ xnb,
    const float* __restrict__ sv, const float* __restrict__ diag,
    const float* __restrict__ x, const float* __restrict__ h,
    const float* __restrict__ wvbT3, const float* __restrict__ mix,
    float* __restrict__ out_x, float* __restrict__ out_h) {
  __shared__ float rA[4], rB[4];
  const size_t NF = (size_t)NB * FD;
  const int i = blockIdx.x, f = threadIdx.x, wid = f >> 6, lane = f & 63;
  const float e0x = __expf(mix[0]), e1x = __expf(mix[2]);
  const float mAx = e0x / (e0x + e1x), mBx = e1x / (e0x + e1x);
  const float e0h = __expf(mix[1]), e1h = __expf(mix[3]);
  const float mAh = e0h / (e0h + e1h), mBh = e1h / (e0h + e1h);

  const size_t rowoff = (size_t)i * FD + f;
  float ax = 0.f, ah = 0.f;
#pragma unroll
  for (int z = 0; z < 8; ++z) {
    ax += bf2f(px[(size_t)z * NF + rowoff]);
    ah += bf2f(ph[(size_t)z * NF + rowoff]);
  }
  const float t2v = t23[(size_t)i * 512 + f];
  const float t3v = t23[(size_t)i * 512 + 256 + f];
  const float xv = bf2f(xnb[rowoff]);

  float rs = wave_reduce_sum(xv * sv[f]);
  float rq = wave_reduce_sum(xv * t2v);
  if (lane == 0) { rA[wid] = rs; rB[wid] = rq; }
  __syncthreads();
  rs = rA[0] + rA[1] + rA[2] + rA[3];
  rq = rB[0] + rB[1] + rB[2] + rB[3];
  const float mean = rs * (1.0f / NB);
  const float var = (rq - (float)NB * mean * mean) * (1.0f / (NB - 1));
  const float sd = sqrtf(fmaxf(var, 0.f));
  const float dg = diag[i];
  const float statsterm = dg * wvbT3[f] + rs * wvbT3[256 + f] + sd * wvbT3[512 + f];

  out_x[rowoff] = mBx * ax + mAx * t2v + x[rowoff];
  const float pre = mBh * ah + mAh * t3v + statsterm;
  out_h[rowoff] = ((pre > 0.f) ? pre : expm1f(pre)) + h[rowoff];
}

// ---------------- batched 64x64 NT GEMM (3 slices, runtime descriptors) -----
struct GDesc {
  const ushort* A; const ushort* B; void* C;
  int lda, ldb, ldc, K, gx, gy, epi;   // epi: 1 bf16 store, 5 splitK fp32
  float alpha; long pstride; int nb;   // nb = total blocks in slice
};

__global__ __launch_bounds__(256) void gemm_batch3(
    GDesc d0, GDesc d1, GDesc d2, int ntot) {
  int flat = blockIdx.x;
  flat = (flat & 7) * (ntot >> 3) + (flat >> 3);   // XCD chunk swizzle (ntot%8==0)
  GDesc d; int l;
  if (flat < d0.nb) { d = d0; l = flat; }
  else if (flat < d0.nb + d1.nb) { d = d1; l = flat - d0.nb; }
  else { d = d2; l = flat - d0.nb - d1.nb; }
  const int bx = l % d.gx;
  const int rest = l / d.gx;
  const int by = rest % d.gy, bz = rest / d.gy;

  __shared__ __align__(16) ushort At[2][64][32];
  __shared__ __align__(16) ushort Bt[2][64][32];
  const int tid = threadIdx.x;
  const int wave = tid >> 6, lane = tid & 63;
  const int wr = wave >> 1, wc = wave & 1;
  const int bi = by * 64, bj = bx * 64;
  const int fr = lane & 15, fq = lane >> 4;
  const int sub = lane >> 2, q = lane & 3;

  f32x4 acc[2][2];
#pragma unroll
  for (int m = 0; m < 2; ++m)
#pragma unroll
    for (int n = 0; n < 2; ++n) acc[m][n] = (f32x4){0.f, 0.f, 0.f, 0.f};

  const int kbase = bz * d.K;
  const int kend = kbase + d.K;

  auto stage = [&](int bufi, int k0) {
    {
      const int row = wave * 16 + sub;
      const int qs = q ^ (row & 3);
      gld16(d.A + (size_t)(bi + row) * d.lda + k0 + qs * 8, &At[bufi][wave * 16][0]);
    }
    {
      const int row = wave * 16 + sub;
      const int qs = q ^ (row & 3);
      gld16(d.B + (size_t)(bj + row) * d.ldb + k0 + qs * 8, &Bt[bufi][wave * 16][0]);
    }
  };

  stage(0, kbase);
  __syncthreads();

  int cur = 0;
  for (int k0 = kbase; k0 < kend; k0 += 32) {
    if (k0 + 32 < kend) stage(cur ^ 1, k0 + 32);
    bf16x8 a[2], b[2];
#pragma unroll
    for (int m = 0; m < 2; ++m) {
      const int row = wr * 32 + m * 16 + fr;
      a[m] = *(const bf16x8*)((const char*)&At[cur][row][0] + ((fq ^ (row & 3)) * 16));
    }
#pragma unroll
    for (int n = 0; n < 2; ++n) {
      const int row = wc * 32 + n * 16 + fr;
      b[n] = *(const bf16x8*)((const char*)&Bt[cur][row][0] + ((fq ^ (row & 3)) * 16));
    }
#pragma unroll
    for (int m = 0; m < 2; ++m)
#pragma unroll
      for (int n = 0; n < 2; ++n)
        acc[m][n] = __builtin_amdgcn_mfma_f32_16x16x32_bf16(a[m], b[n], acc[m][n], 0, 0, 0);
    __syncthreads();
    cur ^= 1;
  }

#pragma unroll
  for (int m = 0; m < 2; ++m)
#pragma unroll
    for (int n = 0; n < 2; ++n)
#pragma unroll
      for (int r = 0; r < 4; ++r) {
        const int row = bi + wr * 32 + m * 16 + fq * 4 + r;
        const int col = bj + wc * 32 + n * 16 + fr;
        const size_t ci = (size_t)row * d.ldc + col;
        const float v = acc[m][n][r];
        if (d.epi == 1) ((ushort*)d.C)[ci] = f2bf(v * d.alpha);
        else ((float*)d.C)[(size_t)bz * d.pstride + ci] = v;
      }
}

// ---------------- NT bf16 MFMA GEMM, 2-phase dbuf + XCD swizzle -------------
// EPI: 0 fp32*alpha | 1 bf16*alpha | 5 splitK fp32 partial | 6 splitK bf16
template <int BM, int BN, int EPI>
__global__ __launch_bounds__(256) void gemm_nt(
    const ushort* __restrict__ A, int lda,
    const ushort* __restrict__ B, int ldb,
    void* __restrict__ Cp, int ldc, int K, float alpha,
    size_t pstride) {
  constexpr int WAVES_N = (BM <= 32) ? 4 : 2;
  constexpr int WAVES_M = 4 / WAVES_N;
  constexpr int WM = BM / WAVES_M, WN = BN / WAVES_N;
  constexpr int MR = WM / 16, NR = WN / 16;
  __shared__ __align__(16) ushort At[2][BM][32];
  __shared__ __align__(16) ushort Bt[2][BN][32];
  const int tid = threadIdx.x;
  const int wave = tid >> 6, lane = tid & 63;
  const int wr = wave / WAVES_N, wc = wave % WAVES_N;

  const int gx = gridDim.x, gy = gridDim.y;
  const int nwg = gx * gy * gridDim.z;
  int flat = blockIdx.x + gx * (blockIdx.y + gy * blockIdx.z);
  if ((nwg & 7) == 0) flat = (flat & 7) * (nwg >> 3) + (flat >> 3);
  const int bx = flat % gx, by = (flat / gx) % gy, bz = flat / (gx * gy);

  const int bi = by * BM, bj = bx * BN;
  const int fr = lane & 15, fq = lane >> 4;
  const int sub = lane >> 2, q = lane & 3;

  f32x4 acc[MR][NR];
#pragma unroll
  for (int m = 0; m < MR; ++m)
#pragma unroll
    for (int n = 0; n < NR; ++n) acc[m][n] = (f32x4){0.f, 0.f, 0.f, 0.f};

  const int kbase = (EPI >= 5) ? bz * K : 0;
  const int kend = kbase + K;

  auto stage = [&](int bufi, int k0) {
    for (int c = wave; c < BM / 16; c += 4) {
      const int row = c * 16 + sub;
      const int qs = q ^ (row & 3);
      gld16(A + (size_t)(bi + row) * lda + k0 + qs * 8, &At[bufi][c * 16][0]);
    }
    for (int c = wave; c < BN / 16; c += 4) {
      const int row = c * 16 + sub;
      const int qs = q ^ (row & 3);
      gld16(B + (size_t)(bj + row) * ldb + k0 + qs * 8, &Bt[bufi][c * 16][0]);
    }
  };

  stage(0, kbase);
  __syncthreads();

  int cur = 0;
  for (int k0 = kbase; k0 < kend; k0 += 32) {
    if (k0 + 32 < kend) stage(cur ^ 1, k0 + 32);
    bf16x8 a[MR], b[NR];
#pragma unroll
    for (int m = 0; m < MR; ++m) {
      const int row = wr * WM + m * 16 + fr;
      a[m] = *(const bf16x8*)((const char*)&At[cur][row][0] + ((fq ^ (row & 3)) * 16));
    }
#pragma unroll
    for (int n = 0; n < NR; ++n) {
      const int row = wc * WN + n * 16 + fr;
      b[n] = *(const bf16x8*)((const char*)&Bt[cur][row][0] + ((fq ^ (row & 3)) * 16));
    }
#pragma unroll
    for (int m = 0; m < MR; ++m)
#pragma unroll
      for (int n = 0; n < NR; ++n)
        acc[m][n] = __builtin_amdgcn_mfma_f32_16x16x32_bf16(a[m], b[n], acc[m][n], 0, 0, 0);
    __syncthreads();
    cur ^= 1;
  }

#pragma unroll
  for (int m = 0; m < MR; ++m)
#pragma unroll
    for (int n = 0; n < NR; ++n)
#pragma unroll
      for (int r = 0; r < 4; ++r) {
        const int row = bi + wr * WM + m * 16 + fq * 4 + r;
        const int col = bj + wc * WN + n * 16 + fr;
        const size_t ci = (size_t)row * ldc + col;
        const float v = acc[m][n][r];
        if (EPI == 0) ((float*)Cp)[ci] = v * alpha;
        else if (EPI == 1) ((ushort*)Cp)[ci] = f2bf(v * alpha);
        else if (EPI == 5) ((float*)Cp)[(size_t)bz * pstride + ci] = v;
        else if (EPI == 6) ((ushort*)Cp)[(size_t)bz * pstride + ci] = f2bf(v);
      }
}

// ---------------------------------------------------------------------------
extern "C" void kernel_launch(void* const* d_in, const int* in_sizes, int n_in,
                              void* d_out, int out_size, void* d_ws, size_t ws_size,
                              hipStream_t stream) {
  const float* h      = (const float*)d_in[0];
  const float* x      = (const float*)d_in[1];
  const float* w_k    = (const float*)d_in[2];
  const float* w_q    = (const float*)d_in[3];
  const float* w_v    = (const float*)d_in[4];
  const float* mixing = (const float*)d_in[5];
  const float* gamma  = (const float*)d_in[6];
  const float* beta   = (const float*)d_in[7];

  float* out_h = (float*)d_out;
  float* out_x = out_h + (size_t)NB * FD;

  char* w = (char*)d_ws;
  ushort* S     = (ushort*)(w + 0);           // 32MB bf16 scores
  ushort* P     = (ushort*)(w + 33554432);    // 32MB
  ushort* PT    = (ushort*)(w + 67108864);    // 32MB
  ushort* hnb   = (ushort*)(w + 100663296);   // 2MB
  ushort* xnb   = (ushort*)(w + 102760448);   // 2MB
  ushort* xnbT  = (ushort*)(w + 104857600);   // 2MB  [256][NB] (stack base)
  ushort* hnbT  = (ushort*)(w + 106954752);   // 2MB  [256][NB] (stack rows 256-511)
  ushort* kq    = (ushort*)(w + 109051904);   // 4MB  [NB][512]
  ushort* hvT   = (ushort*)(w + 113246208);   // 2MB  [256][NB]
  float*  t23   = (float*)(w + 115343360);    // 8MB  [NB][512]
  ushort* t23B  = (ushort*)(w + 123731968);   // 256KB [512][256] (G | Bv)
  ushort* M2T   = (ushort*)(w + 123994112);   // 128KB
  ushort* wkqb  = (ushort*)(w + 124125184);   // 256KB [512][256]
  ushort* wvAb  = (ushort*)(w + 124387328);   // 128KB
  float*  wvbT3 = (float*)(w + 124518400);    // 3KB
  float*  diag  = (float*)(w + 124521472);    // 16KB
  float*  sv    = (float*)(w + 124537856);    // 1KB
  // aliases (disjoint lifetimes):
  float*  Gramp = (float*)(w + 67108864);     // 8MB in PT region (dead before PT)
  ushort* px    = (ushort*)(w + 0);           // 16MB in S region (S dead after softmax)
  ushort* ph    = (ushort*)(w + 16777216);    // 16MB

  rownorm_kernel<<<NB, 256, 0, stream>>>(h, x, gamma, beta, hnb, xnb, diag);
  wcast_kernel<<<FD, 256, 0, stream>>>(w_k, w_q, w_v, wkqb, wvAb, wvbT3);
  transpose2_kernel<<<dim3(FD / 64, NB / 64, 2), 256, 0, stream>>>(
      xnb, xnbT, hnb, hnbT, NB, FD);
  colsum_kernel<<<FD, 256, 0, stream>>>(xnbT, sv);

  // batched: kq = hn @ [w_k;w_q]^T | Gram stacked (split-K 16) | hvT = w_vA @ hn^T
  {
    GDesc dkq = {hnb, wkqb, kq, FD, FD, 512, FD, 8, 64, 1, 1.f, 0, 512};
    GDesc dgr = {xnbT, xnbT, Gramp, NB, NB, 512, NB / 16, 8, 4, 5, 1.f,
                 (long)(256 * 512), 512};
    GDesc dhv = {wvAb, hnb, hvT, FD, FD, NB, FD, 64, 4, 1, 1.f, 0, 256};
    gemm_batch3<<<1280, 256, 0, stream>>>(dkq, dgr, dhv, 1280);
  }
  reduce16g_kernel<<<256 * 512 / 256, 256, 0, stream>>>(Gramp, t23B, M2T);

  // Bv = w_vA @ M2 (via M2T)
  gemm_nt<64, 64, 1><<<dim3(4, 4), 256, 0, stream>>>(
      wvAb, FD, M2T, FD, t23B + 256 * 256, FD, FD, 1.f, 0);

  // t23 = xn @ [G; Bv]^T -> [NB, 512] fp32
  gemm_nt<64, 64, 0><<<dim3(512 / 64, NB / 64), 256, 0, stream>>>(
      xnb, FD, t23B, FD, t23, 512, FD, 1.f, 0);

  // S = bf16((k @ q^T) / 16)
  gemm_nt<128, 128, 1><<<dim3(NB / 128, NB / 128), 256, 0, stream>>>(
      kq, 512, kq + 256, 512, S, NB, FD, 0.0625f, 0);

  // softmax: S -> P ; transpose: P -> PT
  softmax_kernel<<<NB, 256, 0, stream>>>(S, P);
  transpose_kernel<<<dim3(NB / 64, NB / 64), 256, 0, stream>>>(P, PT, NB, NB);

  // aggregation partials: 128x128 tiles, split-K 8
  gemm_nt<128, 128, 6><<<dim3(FD / 128, NB / 128, 8), 256, 0, stream>>>(
      P, NB, xnbT, NB, px, FD, NB / 8, 1.f, (size_t)NB * FD);
  gemm_nt<128, 128, 6><<<dim3(FD / 128, NB / 128, 8), 256, 0, stream>>>(
      PT, NB, hvT, NB, ph, FD, NB / 8, 1.f, (size_t)NB * FD);

  // mega combine -> out_x, out_h
  megacombine_kernel<<<NB, 256, 0, stream>>>(
      px, ph, t23, xnb, sv, diag, x, h, wvbT3, mixing, out_x, out_h);
}

// Round 11
// 125.773 us; speedup vs baseline: 1.3358x; 1.0656x over previous
//
#include <hip/hip_runtime.h>
#include <cstdint>
#include <cstddef>

#define NB 4096
#define FD 256

typedef __attribute__((ext_vector_type(4))) float f32x4;
typedef __attribute__((ext_vector_type(8))) short bf16x8;

__device__ __forceinline__ ushort f2bf(float f) {
  union { float f; uint32_t u; } v; v.f = f;
  uint32_t r = v.u + 0x7fffu + ((v.u >> 16) & 1u);
  return (ushort)(r >> 16);
}
__device__ __forceinline__ float bf2f(ushort b) {
  union { uint32_t u; float f; } v; v.u = ((uint32_t)b) << 16;
  return v.f;
}

__device__ __forceinline__ void gld16(const void* g, void* l) {
  __builtin_amdgcn_global_load_lds(
      (const __attribute__((address_space(1))) char*)g,
      (__attribute__((address_space(3))) char*)l, 16, 0, 0);
}

__device__ __forceinline__ float wave_reduce_sum(float v) {
#pragma unroll
  for (int off = 32; off >= 1; off >>= 1) v += __shfl_xor(v, off);
  return v;
}
__device__ __forceinline__ float wave_reduce_max(float v) {
#pragma unroll
  for (int off = 32; off >= 1; off >>= 1) v = fmaxf(v, __shfl_xor(v, off));
  return v;
}

// ---------------- rownorm + weight casts (merged) ---------------------------
__global__ __launch_bounds__(256) void rownorm_wcast_kernel(
    const float* __restrict__ h, const float* __restrict__ x,
    const float* __restrict__ gamma, const float* __restrict__ beta,
    ushort* __restrict__ hnb, ushort* __restrict__ xnb, float* __restrict__ diag,
    const float* __restrict__ w_k, const float* __restrict__ w_q,
    const float* __restrict__ w_v,
    ushort* __restrict__ wkqb, ushort* __restrict__ wvAb,
    float* __restrict__ wvbT3) {
  __shared__ float rA[4], rB[4], rC[4], rD[4];
  if (blockIdx.x >= NB) {
    const int r = blockIdx.x - NB, t = threadIdx.x;
    wkqb[r * 256 + t] = f2bf(w_k[r * 256 + t]);
    wkqb[(256 + r) * 256 + t] = f2bf(w_q[r * 256 + t]);
    wvAb[r * 256 + t] = f2bf(w_v[(size_t)r * 259 + t]);
    if (t < 3) wvbT3[t * 256 + r] = w_v[(size_t)r * 259 + 256 + t];
    return;
  }
  const int r = blockIdx.x, t = threadIdx.x, wid = t >> 6, lane = t & 63;
  const size_t base = (size_t)r * FD + t;
  const float hv = h[base], xv = x[base];
  float s1 = wave_reduce_sum(hv);
  float s2 = wave_reduce_sum(hv * hv);
  float a1 = wave_reduce_sum(fabsf(xv));
  float q1 = wave_reduce_sum(xv * xv);
  if (lane == 0) { rA[wid] = s1; rB[wid] = s2; rC[wid] = a1; rD[wid] = q1; }
  __syncthreads();
  const float S1 = rA[0] + rA[1] + rA[2] + rA[3];
  const float S2 = rB[0] + rB[1] + rB[2] + rB[3];
  const float L1 = rC[0] + rC[1] + rC[2] + rC[3];
  const float Q1 = rD[0] + rD[1] + rD[2] + rD[3];
  const float mu = S1 * (1.0f / FD);
  const float var = S2 * (1.0f / FD) - mu * mu;
  const float rstd = rsqrtf(var + 1e-5f);
  const float d = fmaxf(L1, 1e-12f), dinv = 1.0f / d;
  hnb[base] = f2bf((hv - mu) * rstd * gamma[t] + beta[t]);
  xnb[base] = f2bf(xv * dinv);
  if (t == 0) diag[r] = Q1 * dinv * dinv;
}

// ---------------- bf16 transpose (64x64 tiles); z selects src/dst pair ------
__global__ __launch_bounds__(256) void transpose2_kernel(
    const ushort* __restrict__ inA, ushort* __restrict__ outA,
    const ushort* __restrict__ inB, ushort* __restrict__ outB, int R, int C) {
  __shared__ ushort tile[64][65];
  const ushort* in = blockIdx.z ? inB : inA;
  ushort* out = blockIdx.z ? outB : outA;
  const int bc = blockIdx.x * 64, br = blockIdx.y * 64;
  const int t = threadIdx.x;
#pragma unroll
  for (int i = 0; i < 16; ++i) {
    const int idx = t + 256 * i;
    const int rr = idx >> 6, cc = idx & 63;
    tile[rr][cc] = in[(size_t)(br + rr) * C + bc + cc];
  }
  __syncthreads();
#pragma unroll
  for (int i = 0; i < 16; ++i) {
    const int idx = t + 256 * i;
    const int rr = idx >> 6, cc = idx & 63;
    out[(size_t)(bc + rr) * R + br + cc] = tile[cc][rr];
  }
}

__global__ __launch_bounds__(256) void transpose_kernel(
    const ushort* __restrict__ in, ushort* __restrict__ out, int R, int C) {
  __shared__ ushort tile[64][65];
  const int bc = blockIdx.x * 64, br = blockIdx.y * 64;
  const int t = threadIdx.x;
#pragma unroll
  for (int i = 0; i < 16; ++i) {
    const int idx = t + 256 * i;
    const int rr = idx >> 6, cc = idx & 63;
    tile[rr][cc] = in[(size_t)(br + rr) * C + bc + cc];
  }
  __syncthreads();
#pragma unroll
  for (int i = 0; i < 16; ++i) {
    const int idx = t + 256 * i;
    const int rr = idx >> 6, cc = idx & 63;
    out[(size_t)(bc + rr) * R + br + cc] = tile[cc][rr];
  }
}

// ---------------- colsum of xn ----------------------------------------------
__global__ __launch_bounds__(256) void colsum_kernel(
    const ushort* __restrict__ xnT, float* __restrict__ s) {
  __shared__ float red[4];
  const int f = blockIdx.x, t = threadIdx.x, wid = t >> 6, lane = t & 63;
  float a = 0.f;
#pragma unroll
  for (int i = 0; i < 16; ++i) a += bf2f(xnT[(size_t)f * NB + t + 256 * i]);
  a = wave_reduce_sum(a);
  if (lane == 0) red[wid] = a;
  __syncthreads();
  if (t == 0) s[f] = red[0] + red[1] + red[2] + red[3];
}

// ---------------- Gram split-K reduce: [16][256][512] -> G | M2T ------------
__global__ __launch_bounds__(256) void reduce16g_kernel(
    const float* __restrict__ in, ushort* __restrict__ t23B,
    ushort* __restrict__ M2T) {
  const int idx = blockIdx.x * 256 + threadIdx.x;   // over 256*512
  const int i = idx >> 9, j = idx & 511;
  float a = 0.f;
#pragma unroll
  for (int z = 0; z < 16; ++z) a += in[(size_t)z * (256 * 512) + idx];
  if (j < 256) t23B[i * 256 + j] = f2bf(a);
  else M2T[i * 256 + (j - 256)] = f2bf(a);
}

// ---------------- row softmax: S bf16 -> P bf16 -----------------------------
__global__ __launch_bounds__(256) void softmax_kernel(
    const ushort* __restrict__ S, ushort* __restrict__ P) {
  __shared__ float red[4];
  const int r = blockIdx.x, t = threadIdx.x, wid = t >> 6, lane = t & 63;
  const uint4* Sr = (const uint4*)(S + (size_t)r * NB);
  float v[16];
  float lmax = -1e30f;
#pragma unroll
  for (int i = 0; i < 2; ++i) {
    const uint4 c = Sr[t + 256 * i];
    const uint32_t w4[4] = {c.x, c.y, c.z, c.w};
#pragma unroll
    for (int j = 0; j < 4; ++j) {
      v[i * 8 + j * 2]     = bf2f((ushort)(w4[j] & 0xffffu));
      v[i * 8 + j * 2 + 1] = bf2f((ushort)(w4[j] >> 16));
    }
  }
#pragma unroll
  for (int u = 0; u < 16; ++u) lmax = fmaxf(lmax, v[u]);
  lmax = wave_reduce_max(lmax);
  if (lane == 0) red[wid] = lmax;
  __syncthreads();
  const float gmax = fmaxf(fmaxf(red[0], red[1]), fmaxf(red[2], red[3]));
  __syncthreads();
  float lsum = 0.f;
#pragma unroll
  for (int u = 0; u < 16; ++u) { v[u] = __expf(v[u] - gmax); lsum += v[u]; }
  lsum = wave_reduce_sum(lsum);
  if (lane == 0) red[wid] = lsum;
  __syncthreads();
  const float pinv = 1.f / (red[0] + red[1] + red[2] + red[3]);
  uint4* Pr = (uint4*)(P + (size_t)r * NB);
#pragma unroll
  for (int i = 0; i < 2; ++i) {
    uint4 o;
    o.x = (uint32_t)f2bf(v[i*8+0] * pinv) | ((uint32_t)f2bf(v[i*8+1] * pinv) << 16);
    o.y = (uint32_t)f2bf(v[i*8+2] * pinv) | ((uint32_t)f2bf(v[i*8+3] * pinv) << 16);
    o.z = (uint32_t)f2bf(v[i*8+4] * pinv) | ((uint32_t)f2bf(v[i*8+5] * pinv) << 16);
    o.w = (uint32_t)f2bf(v[i*8+6] * pinv) | ((uint32_t)f2bf(v[i*8+7] * pinv) << 16);
    Pr[t + 256 * i] = o;
  }
}

// ---------------- mega combine: both outputs --------------------------------
__global__ __launch_bounds__(256) void megacombine_kernel(
    const ushort* __restrict__ px, const ushort* __restrict__ ph,
    const float* __restrict__ t23, const ushort* __restrict__ xnb,
    const float* __restrict__ sv, const float* __restrict__ diag,
    const float* __restrict__ x, const float* __restrict__ h,
    const float* __restrict__ wvbT3, const float* __restrict__ mix,
    float* __restrict__ out_x, float* __restrict__ out_h) {
  __shared__ float rA[4], rB[4];
  const size_t NF = (size_t)NB * FD;
  const int i = blockIdx.x, f = threadIdx.x, wid = f >> 6, lane = f & 63;
  const float e0x = __expf(mix[0]), e1x = __expf(mix[2]);
  const float mAx = e0x / (e0x + e1x), mBx = e1x / (e0x + e1x);
  const float e0h = __expf(mix[1]), e1h = __expf(mix[3]);
  const float mAh = e0h / (e0h + e1h), mBh = e1h / (e0h + e1h);

  const size_t rowoff = (size_t)i * FD + f;
  float ax = 0.f, ah = 0.f;
#pragma unroll
  for (int z = 0; z < 8; ++z) {
    ax += bf2f(px[(size_t)z * NF + rowoff]);
    ah += bf2f(ph[(size_t)z * NF + rowoff]);
  }
  const float t2v = t23[(size_t)i * 512 + f];
  const float t3v = t23[(size_t)i * 512 + 256 + f];
  const float xv = bf2f(xnb[rowoff]);

  float rs = wave_reduce_sum(xv * sv[f]);
  float rq = wave_reduce_sum(xv * t2v);
  if (lane == 0) { rA[wid] = rs; rB[wid] = rq; }
  __syncthreads();
  rs = rA[0] + rA[1] + rA[2] + rA[3];
  rq = rB[0] + rB[1] + rB[2] + rB[3];
  const float mean = rs * (1.0f / NB);
  const float var = (rq - (float)NB * mean * mean) * (1.0f / (NB - 1));
  const float sd = sqrtf(fmaxf(var, 0.f));
  const float dg = diag[i];
  const float statsterm = dg * wvbT3[f] + rs * wvbT3[256 + f] + sd * wvbT3[512 + f];

  out_x[rowoff] = mBx * ax + mAx * t2v + x[rowoff];
  const float pre = mBh * ah + mAh * t3v + statsterm;
  out_h[rowoff] = ((pre > 0.f) ? pre : expm1f(pre)) + h[rowoff];
}

// ---------------- batched 64x64 NT GEMM (3 slices, runtime descriptors) -----
struct GDesc {
  const ushort* A; const ushort* B; void* C;
  int lda, ldb, ldc, K, gx, gy, epi;   // epi: 1 bf16 store, 5 splitK fp32
  float alpha; long pstride; int nb;   // nb = total blocks in slice
};

__global__ __launch_bounds__(256) void gemm_batch3(
    GDesc d0, GDesc d1, GDesc d2, int ntot) {
  int flat = blockIdx.x;
  flat = (flat & 7) * (ntot >> 3) + (flat >> 3);   // XCD chunk swizzle (ntot%8==0)
  GDesc d; int l;
  if (flat < d0.nb) { d = d0; l = flat; }
  else if (flat < d0.nb + d1.nb) { d = d1; l = flat - d0.nb; }
  else { d = d2; l = flat - d0.nb - d1.nb; }
  const int bx = l % d.gx;
  const int rest = l / d.gx;
  const int by = rest % d.gy, bz = rest / d.gy;

  __shared__ __align__(16) ushort At[2][64][32];
  __shared__ __align__(16) ushort Bt[2][64][32];
  const int tid = threadIdx.x;
  const int wave = tid >> 6, lane = tid & 63;
  const int wr = wave >> 1, wc = wave & 1;
  const int bi = by * 64, bj = bx * 64;
  const int fr = lane & 15, fq = lane >> 4;
  const int sub = lane >> 2, q = lane & 3;

  f32x4 acc[2][2];
#pragma unroll
  for (int m = 0; m < 2; ++m)
#pragma unroll
    for (int n = 0; n < 2; ++n) acc[m][n] = (f32x4){0.f, 0.f, 0.f, 0.f};

  const int kbase = bz * d.K;
  const int kend = kbase + d.K;

  auto stage = [&](int bufi, int k0) {
    {
      const int row = wave * 16 + sub;
      const int qs = q ^ (row & 3);
      gld16(d.A + (size_t)(bi + row) * d.lda + k0 + qs * 8, &At[bufi][wave * 16][0]);
    }
    {
      const int row = wave * 16 + sub;
      const int qs = q ^ (row & 3);
      gld16(d.B + (size_t)(bj + row) * d.ldb + k0 + qs * 8, &Bt[bufi][wave * 16][0]);
    }
  };

  stage(0, kbase);
  __syncthreads();

  int cur = 0;
  for (int k0 = kbase; k0 < kend; k0 += 32) {
    if (k0 + 32 < kend) stage(cur ^ 1, k0 + 32);
    bf16x8 a[2], b[2];
#pragma unroll
    for (int m = 0; m < 2; ++m) {
      const int row = wr * 32 + m * 16 + fr;
      a[m] = *(const bf16x8*)((const char*)&At[cur][row][0] + ((fq ^ (row & 3)) * 16));
    }
#pragma unroll
    for (int n = 0; n < 2; ++n) {
      const int row = wc * 32 + n * 16 + fr;
      b[n] = *(const bf16x8*)((const char*)&Bt[cur][row][0] + ((fq ^ (row & 3)) * 16));
    }
#pragma unroll
    for (int m = 0; m < 2; ++m)
#pragma unroll
      for (int n = 0; n < 2; ++n)
        acc[m][n] = __builtin_amdgcn_mfma_f32_16x16x32_bf16(a[m], b[n], acc[m][n], 0, 0, 0);
    __syncthreads();
    cur ^= 1;
  }

#pragma unroll
  for (int m = 0; m < 2; ++m)
#pragma unroll
    for (int n = 0; n < 2; ++n)
#pragma unroll
      for (int r = 0; r < 4; ++r) {
        const int row = bi + wr * 32 + m * 16 + fq * 4 + r;
        const int col = bj + wc * 32 + n * 16 + fr;
        const size_t ci = (size_t)row * d.ldc + col;
        const float v = acc[m][n][r];
        if (d.epi == 1) ((ushort*)d.C)[ci] = f2bf(v * d.alpha);
        else ((float*)d.C)[(size_t)bz * d.pstride + ci] = v;
      }
}

// ---------------- merged aggregation GEMM: both P@xnT and PT@hvT ------------
// grid (2, 32, 16): z<8 -> px[z] = (P @ xnT)[kchunk z]; z>=8 -> ph[z-8].
__global__ __launch_bounds__(256) void gemm_agg(
    const ushort* __restrict__ P, const ushort* __restrict__ PT,
    const ushort* __restrict__ xnT, const ushort* __restrict__ hvT,
    ushort* __restrict__ px, ushort* __restrict__ ph) {
  __shared__ __align__(16) ushort At[2][128][32];
  __shared__ __align__(16) ushort Bt[2][128][32];
  const int tid = threadIdx.x;
  const int wave = tid >> 6, lane = tid & 63;
  const int wr = wave >> 1, wc = wave & 1;

  const int nwg = 1024;
  int flat = blockIdx.x + 2 * (blockIdx.y + 32 * blockIdx.z);
  flat = (flat & 7) * (nwg >> 3) + (flat >> 3);
  const int bx = flat % 2, by = (flat / 2) % 32, bz = flat / 64;
  const int sel = bz >> 3, kz = bz & 7;

  const ushort* A = sel ? PT : P;
  const ushort* B = sel ? hvT : xnT;
  ushort* C = sel ? ph : px;

  const int bi = by * 128, bj = bx * 128;
  const int fr = lane & 15, fq = lane >> 4;
  const int sub = lane >> 2, q = lane & 3;

  f32x4 acc[4][4];
#pragma unroll
  for (int m = 0; m < 4; ++m)
#pragma unroll
    for (int n = 0; n < 4; ++n) acc[m][n] = (f32x4){0.f, 0.f, 0.f, 0.f};

  const int kbase = kz * 512;
  const int kend = kbase + 512;

  auto stage = [&](int bufi, int k0) {
    for (int c = wave; c < 8; c += 4) {
      const int row = c * 16 + sub;
      const int qs = q ^ (row & 3);
      gld16(A + (size_t)(bi + row) * NB + k0 + qs * 8, &At[bufi][c * 16][0]);
    }
    for (int c = wave; c < 8; c += 4) {
      const int row = c * 16 + sub;
      const int qs = q ^ (row & 3);
      gld16(B + (size_t)(bj + row) * NB + k0 + qs * 8, &Bt[bufi][c * 16][0]);
    }
  };

  stage(0, kbase);
  __syncthreads();

  int cur = 0;
  for (int k0 = kbase; k0 < kend; k0 += 32) {
    if (k0 + 32 < kend) stage(cur ^ 1, k0 + 32);
    bf16x8 a[4], b[4];
#pragma unroll
    for (int m = 0; m < 4; ++m) {
      const int row = wr * 64 + m * 16 + fr;
      a[m] = *(const bf16x8*)((const char*)&At[cur][row][0] + ((fq ^ (row & 3)) * 16));
    }
#pragma unroll
    for (int n = 0; n < 4; ++n) {
      const int row = wc * 64 + n * 16 + fr;
      b[n] = *(const bf16x8*)((const char*)&Bt[cur][row][0] + ((fq ^ (row & 3)) * 16));
    }
#pragma unroll
    for (int m = 0; m < 4; ++m)
#pragma unroll
      for (int n = 0; n < 4; ++n)
        acc[m][n] = __builtin_amdgcn_mfma_f32_16x16x32_bf16(a[m], b[n], acc[m][n], 0, 0, 0);
    __syncthreads();
    cur ^= 1;
  }

#pragma unroll
  for (int m = 0; m < 4; ++m)
#pragma unroll
    for (int n = 0; n < 4; ++n)
#pragma unroll
      for (int r = 0; r < 4; ++r) {
        const int row = bi + wr * 64 + m * 16 + fq * 4 + r;
        const int col = bj + wc * 64 + n * 16 + fr;
        C[(size_t)kz * ((size_t)NB * FD) + (size_t)row * FD + col] = f2bf(acc[m][n][r]);
      }
}

// ---------------- NT bf16 MFMA GEMM, 2-phase dbuf + XCD swizzle -------------
// EPI: 0 fp32*alpha | 1 bf16*alpha | 5 splitK fp32 partial | 6 splitK bf16
template <int BM, int BN, int EPI>
__global__ __launch_bounds__(256) void gemm_nt(
    const ushort* __restrict__ A, int lda,
    const ushort* __restrict__ B, int ldb,
    void* __restrict__ Cp, int ldc, int K, float alpha,
    size_t pstride) {
  constexpr int WAVES_N = (BM <= 32) ? 4 : 2;
  constexpr int WAVES_M = 4 / WAVES_N;
  constexpr int WM = BM / WAVES_M, WN = BN / WAVES_N;
  constexpr int MR = WM / 16, NR = WN / 16;
  __shared__ __align__(16) ushort At[2][BM][32];
  __shared__ __align__(16) ushort Bt[2][BN][32];
  const int tid = threadIdx.x;
  const int wave = tid >> 6, lane = tid & 63;
  const int wr = wave / WAVES_N, wc = wave % WAVES_N;

  const int gx = gridDim.x, gy = gridDim.y;
  const int nwg = gx * gy * gridDim.z;
  int flat = blockIdx.x + gx * (blockIdx.y + gy * blockIdx.z);
  if ((nwg & 7) == 0) flat = (flat & 7) * (nwg >> 3) + (flat >> 3);
  const int bx = flat % gx, by = (flat / gx) % gy, bz = flat / (gx * gy);

  const int bi = by * BM, bj = bx * BN;
  const int fr = lane & 15, fq = lane >> 4;
  const int sub = lane >> 2, q = lane & 3;

  f32x4 acc[MR][NR];
#pragma unroll
  for (int m = 0; m < MR; ++m)
#pragma unroll
    for (int n = 0; n < NR; ++n) acc[m][n] = (f32x4){0.f, 0.f, 0.f, 0.f};

  const int kbase = (EPI >= 5) ? bz * K : 0;
  const int kend = kbase + K;

  auto stage = [&](int bufi, int k0) {
    for (int c = wave; c < BM / 16; c += 4) {
      const int row = c * 16 + sub;
      const int qs = q ^ (row & 3);
      gld16(A + (size_t)(bi + row) * lda + k0 + qs * 8, &At[bufi][c * 16][0]);
    }
    for (int c = wave; c < BN / 16; c += 4) {
      const int row = c * 16 + sub;
      const int qs = q ^ (row & 3);
      gld16(B + (size_t)(bj + row) * ldb + k0 + qs * 8, &Bt[bufi][c * 16][0]);
    }
  };

  stage(0, kbase);
  __syncthreads();

  int cur = 0;
  for (int k0 = kbase; k0 < kend; k0 += 32) {
    if (k0 + 32 < kend) stage(cur ^ 1, k0 + 32);
    bf16x8 a[MR], b[NR];
#pragma unroll
    for (int m = 0; m < MR; ++m) {
      const int row = wr * WM + m * 16 + fr;
      a[m] = *(const bf16x8*)((const char*)&At[cur][row][0] + ((fq ^ (row & 3)) * 16));
    }
#pragma unroll
    for (int n = 0; n < NR; ++n) {
      const int row = wc * WN + n * 16 + fr;
      b[n] = *(const bf16x8*)((const char*)&Bt[cur][row][0] + ((fq ^ (row & 3)) * 16));
    }
#pragma unroll
    for (int m = 0; m < MR; ++m)
#pragma unroll
      for (int n = 0; n < NR; ++n)
        acc[m][n] = __builtin_amdgcn_mfma_f32_16x16x32_bf16(a[m], b[n], acc[m][n], 0, 0, 0);
    __syncthreads();
    cur ^= 1;
  }

#pragma unroll
  for (int m = 0; m < MR; ++m)
#pragma unroll
    for (int n = 0; n < NR; ++n)
#pragma unroll
      for (int r = 0; r < 4; ++r) {
        const int row = bi + wr * WM + m * 16 + fq * 4 + r;
        const int col = bj + wc * WN + n * 16 + fr;
        const size_t ci = (size_t)row * ldc + col;
        const float v = acc[m][n][r];
        if (EPI == 0) ((float*)Cp)[ci] = v * alpha;
        else if (EPI == 1) ((ushort*)Cp)[ci] = f2bf(v * alpha);
        else if (EPI == 5) ((float*)Cp)[(size_t)bz * pstride + ci] = v;
        else if (EPI == 6) ((ushort*)Cp)[(size_t)bz * pstride + ci] = f2bf(v);
      }
}

// ---------------------------------------------------------------------------
extern "C" void kernel_launch(void* const* d_in, const int* in_sizes, int n_in,
                              void* d_out, int out_size, void* d_ws, size_t ws_size,
                              hipStream_t stream) {
  const float* h      = (const float*)d_in[0];
  const float* x      = (const float*)d_in[1];
  const float* w_k    = (const float*)d_in[2];
  const float* w_q    = (const float*)d_in[3];
  const float* w_v    = (const float*)d_in[4];
  const float* mixing = (const float*)d_in[5];
  const float* gamma  = (const float*)d_in[6];
  const float* beta   = (const float*)d_in[7];

  float* out_h = (float*)d_out;
  float* out_x = out_h + (size_t)NB * FD;

  char* w = (char*)d_ws;
  ushort* S     = (ushort*)(w + 0);           // 32MB bf16 scores
  ushort* P     = (ushort*)(w + 33554432);    // 32MB
  ushort* PT    = (ushort*)(w + 67108864);    // 32MB
  ushort* hnb   = (ushort*)(w + 100663296);   // 2MB
  ushort* xnb   = (ushort*)(w + 102760448);   // 2MB
  ushort* xnbT  = (ushort*)(w + 104857600);   // 2MB  [256][NB] (stack base)
  ushort* hnbT  = (ushort*)(w + 106954752);   // 2MB  [256][NB] (stack rows 256-511)
  ushort* kq    = (ushort*)(w + 109051904);   // 4MB  [NB][512]
  ushort* hvT   = (ushort*)(w + 113246208);   // 2MB  [256][NB]
  float*  t23   = (float*)(w + 115343360);    // 8MB  [NB][512]
  ushort* t23B  = (ushort*)(w + 123731968);   // 256KB [512][256] (G | Bv)
  ushort* M2T   = (ushort*)(w + 123994112);   // 128KB
  ushort* wkqb  = (ushort*)(w + 124125184);   // 256KB [512][256]
  ushort* wvAb  = (ushort*)(w + 124387328);   // 128KB
  float*  wvbT3 = (float*)(w + 124518400);    // 3KB
  float*  diag  = (float*)(w + 124521472);    // 16KB
  float*  sv    = (float*)(w + 124537856);    // 1KB
  // aliases (disjoint lifetimes):
  float*  Gramp = (float*)(w + 67108864);     // 8MB in PT region (dead before PT)
  ushort* px    = (ushort*)(w + 0);           // 16MB in S region (S dead after softmax)
  ushort* ph    = (ushort*)(w + 16777216);    // 16MB

  rownorm_wcast_kernel<<<NB + FD, 256, 0, stream>>>(
      h, x, gamma, beta, hnb, xnb, diag, w_k, w_q, w_v, wkqb, wvAb, wvbT3);
  transpose2_kernel<<<dim3(FD / 64, NB / 64, 2), 256, 0, stream>>>(
      xnb, xnbT, hnb, hnbT, NB, FD);
  colsum_kernel<<<FD, 256, 0, stream>>>(xnbT, sv);

  // batched: kq = hn @ [w_k;w_q]^T | Gram stacked (split-K 16) | hvT = w_vA @ hn^T
  {
    GDesc dkq = {hnb, wkqb, kq, FD, FD, 512, FD, 8, 64, 1, 1.f, 0, 512};
    GDesc dgr = {xnbT, xnbT, Gramp, NB, NB, 512, NB / 16, 8, 4, 5, 1.f,
                 (long)(256 * 512), 512};
    GDesc dhv = {wvAb, hnb, hvT, FD, FD, NB, FD, 64, 4, 1, 1.f, 0, 256};
    gemm_batch3<<<1280, 256, 0, stream>>>(dkq, dgr, dhv, 1280);
  }
  reduce16g_kernel<<<256 * 512 / 256, 256, 0, stream>>>(Gramp, t23B, M2T);

  // Bv = w_vA @ M2 (via M2T)
  gemm_nt<64, 64, 1><<<dim3(4, 4), 256, 0, stream>>>(
      wvAb, FD, M2T, FD, t23B + 256 * 256, FD, FD, 1.f, 0);

  // t23 = xn @ [G; Bv]^T -> [NB, 512] fp32
  gemm_nt<64, 64, 0><<<dim3(512 / 64, NB / 64), 256, 0, stream>>>(
      xnb, FD, t23B, FD, t23, 512, FD, 1.f, 0);

  // S = bf16((k @ q^T) / 16)
  gemm_nt<128, 128, 1><<<dim3(NB / 128, NB / 128), 256, 0, stream>>>(
      kq, 512, kq + 256, 512, S, NB, FD, 0.0625f, 0);

  // softmax: S -> P ; transpose: P -> PT
  softmax_kernel<<<NB, 256, 0, stream>>>(S, P);
  transpose_kernel<<<dim3(NB / 64, NB / 64), 256, 0, stream>>>(P, PT, NB, NB);

  // merged aggregation partials: 128x128 tiles, split-K 8, both GEMMs
  gemm_agg<<<dim3(2, 32, 16), 256, 0, stream>>>(P, PT, xnbT, hvT, px, ph);

  // mega combine -> out_x, out_h
  megacombine_kernel<<<NB, 256, 0, stream>>>(
      px, ph, t23, xnb, sv, diag, x, h, wvbT3, mixing, out_x, out_h);
}

// Round 12
// 123.437 us; speedup vs baseline: 1.3610x; 1.0189x over previous
//
#include <hip/hip_runtime.h>
#include <cstdint>
#include <cstddef>

#define NB 4096
#define FD 256

typedef __attribute__((ext_vector_type(4))) float f32x4;
typedef __attribute__((ext_vector_type(8))) short bf16x8;

__device__ __forceinline__ ushort f2bf(float f) {
  union { float f; uint32_t u; } v; v.f = f;
  uint32_t r = v.u + 0x7fffu + ((v.u >> 16) & 1u);
  return (ushort)(r >> 16);
}
__device__ __forceinline__ float bf2f(ushort b) {
  union { uint32_t u; float f; } v; v.u = ((uint32_t)b) << 16;
  return v.f;
}

__device__ __forceinline__ void gld16(const void* g, void* l) {
  __builtin_amdgcn_global_load_lds(
      (const __attribute__((address_space(1))) char*)g,
      (__attribute__((address_space(3))) char*)l, 16, 0, 0);
}

__device__ __forceinline__ float wave_reduce_sum(float v) {
#pragma unroll
  for (int off = 32; off >= 1; off >>= 1) v += __shfl_xor(v, off);
  return v;
}
__device__ __forceinline__ float wave_reduce_max(float v) {
#pragma unroll
  for (int off = 32; off >= 1; off >>= 1) v = fmaxf(v, __shfl_xor(v, off));
  return v;
}

// ---------------- rownorm + weight casts (merged) ---------------------------
__global__ __launch_bounds__(256) void rownorm_wcast_kernel(
    const float* __restrict__ h, const float* __restrict__ x,
    const float* __restrict__ gamma, const float* __restrict__ beta,
    ushort* __restrict__ hnb, ushort* __restrict__ xnb, float* __restrict__ diag,
    const float* __restrict__ w_k, const float* __restrict__ w_q,
    const float* __restrict__ w_v,
    ushort* __restrict__ wkqb, ushort* __restrict__ wvAb,
    float* __restrict__ wvbT3) {
  __shared__ float rA[4], rB[4], rC[4], rD[4];
  if (blockIdx.x >= NB) {
    const int r = blockIdx.x - NB, t = threadIdx.x;
    wkqb[r * 256 + t] = f2bf(w_k[r * 256 + t]);
    wkqb[(256 + r) * 256 + t] = f2bf(w_q[r * 256 + t]);
    wvAb[r * 256 + t] = f2bf(w_v[(size_t)r * 259 + t]);
    if (t < 3) wvbT3[t * 256 + r] = w_v[(size_t)r * 259 + 256 + t];
    return;
  }
  const int r = blockIdx.x, t = threadIdx.x, wid = t >> 6, lane = t & 63;
  const size_t base = (size_t)r * FD + t;
  const float hv = h[base], xv = x[base];
  float s1 = wave_reduce_sum(hv);
  float s2 = wave_reduce_sum(hv * hv);
  float a1 = wave_reduce_sum(fabsf(xv));
  float q1 = wave_reduce_sum(xv * xv);
  if (lane == 0) { rA[wid] = s1; rB[wid] = s2; rC[wid] = a1; rD[wid] = q1; }
  __syncthreads();
  const float S1 = rA[0] + rA[1] + rA[2] + rA[3];
  const float S2 = rB[0] + rB[1] + rB[2] + rB[3];
  const float L1 = rC[0] + rC[1] + rC[2] + rC[3];
  const float Q1 = rD[0] + rD[1] + rD[2] + rD[3];
  const float mu = S1 * (1.0f / FD);
  const float var = S2 * (1.0f / FD) - mu * mu;
  const float rstd = rsqrtf(var + 1e-5f);
  const float d = fmaxf(L1, 1e-12f), dinv = 1.0f / d;
  hnb[base] = f2bf((hv - mu) * rstd * gamma[t] + beta[t]);
  xnb[base] = f2bf(xv * dinv);
  if (t == 0) diag[r] = Q1 * dinv * dinv;
}

// ---------------- bf16 transpose (64x64 tiles); z selects src/dst pair ------
__global__ __launch_bounds__(256) void transpose2_kernel(
    const ushort* __restrict__ inA, ushort* __restrict__ outA,
    const ushort* __restrict__ inB, ushort* __restrict__ outB, int R, int C) {
  __shared__ ushort tile[64][65];
  const ushort* in = blockIdx.z ? inB : inA;
  ushort* out = blockIdx.z ? outB : outA;
  const int bc = blockIdx.x * 64, br = blockIdx.y * 64;
  const int t = threadIdx.x;
#pragma unroll
  for (int i = 0; i < 16; ++i) {
    const int idx = t + 256 * i;
    const int rr = idx >> 6, cc = idx & 63;
    tile[rr][cc] = in[(size_t)(br + rr) * C + bc + cc];
  }
  __syncthreads();
#pragma unroll
  for (int i = 0; i < 16; ++i) {
    const int idx = t + 256 * i;
    const int rr = idx >> 6, cc = idx & 63;
    out[(size_t)(bc + rr) * R + br + cc] = tile[cc][rr];
  }
}

// ---------------- vectorized bf16 transpose (ushort4 both global sides) -----
__global__ __launch_bounds__(256) void transpose4_kernel(
    const ushort* __restrict__ in, ushort* __restrict__ out, int R, int C) {
  __shared__ ushort tile[64][66];
  const int bc = blockIdx.x * 64, br = blockIdx.y * 64;
  const int t = threadIdx.x;
  const int c4 = (t & 15) * 4;   // 0..60 step 4
  const int r0 = t >> 4;         // 0..15
#pragma unroll
  for (int i = 0; i < 4; ++i) {
    const int rr = r0 + 16 * i;
    *(ushort4*)&tile[rr][c4] =
        *(const ushort4*)(in + (size_t)(br + rr) * C + bc + c4);
  }
  __syncthreads();
#pragma unroll
  for (int i = 0; i < 4; ++i) {
    const int ro = r0 + 16 * i;   // output row within bc-tile
    ushort4 o;
    o.x = tile[c4 + 0][ro];
    o.y = tile[c4 + 1][ro];
    o.z = tile[c4 + 2][ro];
    o.w = tile[c4 + 3][ro];
    *(ushort4*)(out + (size_t)(bc + ro) * R + br + c4) = o;
  }
}

// ---------------- colsum of xn ----------------------------------------------
__global__ __launch_bounds__(256) void colsum_kernel(
    const ushort* __restrict__ xnT, float* __restrict__ s) {
  __shared__ float red[4];
  const int f = blockIdx.x, t = threadIdx.x, wid = t >> 6, lane = t & 63;
  float a = 0.f;
#pragma unroll
  for (int i = 0; i < 16; ++i) a += bf2f(xnT[(size_t)f * NB + t + 256 * i]);
  a = wave_reduce_sum(a);
  if (lane == 0) red[wid] = a;
  __syncthreads();
  if (t == 0) s[f] = red[0] + red[1] + red[2] + red[3];
}

// ---------------- Gram split-K reduce: [16][256][512] -> G | M2T ------------
__global__ __launch_bounds__(256) void reduce16g_kernel(
    const float* __restrict__ in, ushort* __restrict__ t23B,
    ushort* __restrict__ M2T) {
  const int idx = blockIdx.x * 256 + threadIdx.x;   // over 256*512
  const int i = idx >> 9, j = idx & 511;
  float a = 0.f;
#pragma unroll
  for (int z = 0; z < 16; ++z) a += in[(size_t)z * (256 * 512) + idx];
  if (j < 256) t23B[i * 256 + j] = f2bf(a);
  else M2T[i * 256 + (j - 256)] = f2bf(a);
}

// ---------------- row softmax: S bf16 -> P bf16 -----------------------------
__global__ __launch_bounds__(256) void softmax_kernel(
    const ushort* __restrict__ S, ushort* __restrict__ P) {
  __shared__ float red[4];
  const int r = blockIdx.x, t = threadIdx.x, wid = t >> 6, lane = t & 63;
  const uint4* Sr = (const uint4*)(S + (size_t)r * NB);
  float v[16];
  float lmax = -1e30f;
#pragma unroll
  for (int i = 0; i < 2; ++i) {
    const uint4 c = Sr[t + 256 * i];
    const uint32_t w4[4] = {c.x, c.y, c.z, c.w};
#pragma unroll
    for (int j = 0; j < 4; ++j) {
      v[i * 8 + j * 2]     = bf2f((ushort)(w4[j] & 0xffffu));
      v[i * 8 + j * 2 + 1] = bf2f((ushort)(w4[j] >> 16));
    }
  }
#pragma unroll
  for (int u = 0; u < 16; ++u) lmax = fmaxf(lmax, v[u]);
  lmax = wave_reduce_max(lmax);
  if (lane == 0) red[wid] = lmax;
  __syncthreads();
  const float gmax = fmaxf(fmaxf(red[0], red[1]), fmaxf(red[2], red[3]));
  __syncthreads();
  float lsum = 0.f;
#pragma unroll
  for (int u = 0; u < 16; ++u) { v[u] = __expf(v[u] - gmax); lsum += v[u]; }
  lsum = wave_reduce_sum(lsum);
  if (lane == 0) red[wid] = lsum;
  __syncthreads();
  const float pinv = 1.f / (red[0] + red[1] + red[2] + red[3]);
  uint4* Pr = (uint4*)(P + (size_t)r * NB);
#pragma unroll
  for (int i = 0; i < 2; ++i) {
    uint4 o;
    o.x = (uint32_t)f2bf(v[i*8+0] * pinv) | ((uint32_t)f2bf(v[i*8+1] * pinv) << 16);
    o.y = (uint32_t)f2bf(v[i*8+2] * pinv) | ((uint32_t)f2bf(v[i*8+3] * pinv) << 16);
    o.z = (uint32_t)f2bf(v[i*8+4] * pinv) | ((uint32_t)f2bf(v[i*8+5] * pinv) << 16);
    o.w = (uint32_t)f2bf(v[i*8+6] * pinv) | ((uint32_t)f2bf(v[i*8+7] * pinv) << 16);
    Pr[t + 256 * i] = o;
  }
}

// ---------------- mega combine: both outputs --------------------------------
__global__ __launch_bounds__(256) void megacombine_kernel(
    const ushort* __restrict__ px, const ushort* __restrict__ ph,
    const float* __restrict__ t23, const ushort* __restrict__ xnb,
    const float* __restrict__ sv, const float* __restrict__ diag,
    const float* __restrict__ x, const float* __restrict__ h,
    const float* __restrict__ wvbT3, const float* __restrict__ mix,
    float* __restrict__ out_x, float* __restrict__ out_h) {
  __shared__ float rA[4], rB[4];
  const size_t NF = (size_t)NB * FD;
  const int i = blockIdx.x, f = threadIdx.x, wid = f >> 6, lane = f & 63;
  const float e0x = __expf(mix[0]), e1x = __expf(mix[2]);
  const float mAx = e0x / (e0x + e1x), mBx = e1x / (e0x + e1x);
  const float e0h = __expf(mix[1]), e1h = __expf(mix[3]);
  const float mAh = e0h / (e0h + e1h), mBh = e1h / (e0h + e1h);

  const size_t rowoff = (size_t)i * FD + f;
  float ax = 0.f, ah = 0.f;
#pragma unroll
  for (int z = 0; z < 4; ++z) {
    ax += bf2f(px[(size_t)z * NF + rowoff]);
    ah += bf2f(ph[(size_t)z * NF + rowoff]);
  }
  const float t2v = t23[(size_t)i * 512 + f];
  const float t3v = t23[(size_t)i * 512 + 256 + f];
  const float xv = bf2f(xnb[rowoff]);

  float rs = wave_reduce_sum(xv * sv[f]);
  float rq = wave_reduce_sum(xv * t2v);
  if (lane == 0) { rA[wid] = rs; rB[wid] = rq; }
  __syncthreads();
  rs = rA[0] + rA[1] + rA[2] + rA[3];
  rq = rB[0] + rB[1] + rB[2] + rB[3];
  const float mean = rs * (1.0f / NB);
  const float var = (rq - (float)NB * mean * mean) * (1.0f / (NB - 1));
  const float sd = sqrtf(fmaxf(var, 0.f));
  const float dg = diag[i];
  const float statsterm = dg * wvbT3[f] + rs * wvbT3[256 + f] + sd * wvbT3[512 + f];

  out_x[rowoff] = mBx * ax + mAx * t2v + x[rowoff];
  const float pre = mBh * ah + mAh * t3v + statsterm;
  out_h[rowoff] = ((pre > 0.f) ? pre : expm1f(pre)) + h[rowoff];
}

// ---------------- batched 64x64 NT GEMM (3 slices, runtime descriptors) -----
struct GDesc {
  const ushort* A; const ushort* B; void* C;
  int lda, ldb, ldc, K, gx, gy, epi;   // epi: 1 bf16 store, 5 splitK fp32
  float alpha; long pstride; int nb;   // nb = total blocks in slice
};

__global__ __launch_bounds__(256) void gemm_batch3(
    GDesc d0, GDesc d1, GDesc d2, int ntot) {
  int flat = blockIdx.x;
  flat = (flat & 7) * (ntot >> 3) + (flat >> 3);   // XCD chunk swizzle (ntot%8==0)
  GDesc d; int l;
  if (flat < d0.nb) { d = d0; l = flat; }
  else if (flat < d0.nb + d1.nb) { d = d1; l = flat - d0.nb; }
  else { d = d2; l = flat - d0.nb - d1.nb; }
  const int bx = l % d.gx;
  const int rest = l / d.gx;
  const int by = rest % d.gy, bz = rest / d.gy;

  __shared__ __align__(16) ushort At[2][64][32];
  __shared__ __align__(16) ushort Bt[2][64][32];
  const int tid = threadIdx.x;
  const int wave = tid >> 6, lane = tid & 63;
  const int wr = wave >> 1, wc = wave & 1;
  const int bi = by * 64, bj = bx * 64;
  const int fr = lane & 15, fq = lane >> 4;
  const int sub = lane >> 2, q = lane & 3;

  f32x4 acc[2][2];
#pragma unroll
  for (int m = 0; m < 2; ++m)
#pragma unroll
    for (int n = 0; n < 2; ++n) acc[m][n] = (f32x4){0.f, 0.f, 0.f, 0.f};

  const int kbase = bz * d.K;
  const int kend = kbase + d.K;

  auto stage = [&](int bufi, int k0) {
    {
      const int row = wave * 16 + sub;
      const int qs = q ^ (row & 3);
      gld16(d.A + (size_t)(bi + row) * d.lda + k0 + qs * 8, &At[bufi][wave * 16][0]);
    }
    {
      const int row = wave * 16 + sub;
      const int qs = q ^ (row & 3);
      gld16(d.B + (size_t)(bj + row) * d.ldb + k0 + qs * 8, &Bt[bufi][wave * 16][0]);
    }
  };

  stage(0, kbase);
  __syncthreads();

  int cur = 0;
  for (int k0 = kbase; k0 < kend; k0 += 32) {
    if (k0 + 32 < kend) stage(cur ^ 1, k0 + 32);
    bf16x8 a[2], b[2];
#pragma unroll
    for (int m = 0; m < 2; ++m) {
      const int row = wr * 32 + m * 16 + fr;
      a[m] = *(const bf16x8*)((const char*)&At[cur][row][0] + ((fq ^ (row & 3)) * 16));
    }
#pragma unroll
    for (int n = 0; n < 2; ++n) {
      const int row = wc * 32 + n * 16 + fr;
      b[n] = *(const bf16x8*)((const char*)&Bt[cur][row][0] + ((fq ^ (row & 3)) * 16));
    }
#pragma unroll
    for (int m = 0; m < 2; ++m)
#pragma unroll
      for (int n = 0; n < 2; ++n)
        acc[m][n] = __builtin_amdgcn_mfma_f32_16x16x32_bf16(a[m], b[n], acc[m][n], 0, 0, 0);
    __syncthreads();
    cur ^= 1;
  }

#pragma unroll
  for (int m = 0; m < 2; ++m)
#pragma unroll
    for (int n = 0; n < 2; ++n)
#pragma unroll
      for (int r = 0; r < 4; ++r) {
        const int row = bi + wr * 32 + m * 16 + fq * 4 + r;
        const int col = bj + wc * 32 + n * 16 + fr;
        const size_t ci = (size_t)row * d.ldc + col;
        const float v = acc[m][n][r];
        if (d.epi == 1) ((ushort*)d.C)[ci] = f2bf(v * d.alpha);
        else ((float*)d.C)[(size_t)bz * d.pstride + ci] = v;
      }
}

// ---------------- merged aggregation GEMM: both P@xnT and PT@hvT ------------
// grid (2, 32, 8): z<4 -> px[z] = (P @ xnT)[kchunk z]; z>=4 -> ph[z-4].
__global__ __launch_bounds__(256) void gemm_agg(
    const ushort* __restrict__ P, const ushort* __restrict__ PT,
    const ushort* __restrict__ xnT, const ushort* __restrict__ hvT,
    ushort* __restrict__ px, ushort* __restrict__ ph) {
  __shared__ __align__(16) ushort At[2][128][32];
  __shared__ __align__(16) ushort Bt[2][128][32];
  const int tid = threadIdx.x;
  const int wave = tid >> 6, lane = tid & 63;
  const int wr = wave >> 1, wc = wave & 1;

  const int nwg = 512;
  int flat = blockIdx.x + 2 * (blockIdx.y + 32 * blockIdx.z);
  flat = (flat & 7) * (nwg >> 3) + (flat >> 3);
  const int bx = flat % 2, by = (flat / 2) % 32, bz = flat / 64;
  const int sel = bz >> 2, kz = bz & 3;

  const ushort* A = sel ? PT : P;
  const ushort* B = sel ? hvT : xnT;
  ushort* C = sel ? ph : px;

  const int bi = by * 128, bj = bx * 128;
  const int fr = lane & 15, fq = lane >> 4;
  const int sub = lane >> 2, q = lane & 3;

  f32x4 acc[4][4];
#pragma unroll
  for (int m = 0; m < 4; ++m)
#pragma unroll
    for (int n = 0; n < 4; ++n) acc[m][n] = (f32x4){0.f, 0.f, 0.f, 0.f};

  const int kbase = kz * 1024;
  const int kend = kbase + 1024;

  auto stage = [&](int bufi, int k0) {
    for (int c = wave; c < 8; c += 4) {
      const int row = c * 16 + sub;
      const int qs = q ^ (row & 3);
      gld16(A + (size_t)(bi + row) * NB + k0 + qs * 8, &At[bufi][c * 16][0]);
    }
    for (int c = wave; c < 8; c += 4) {
      const int row = c * 16 + sub;
      const int qs = q ^ (row & 3);
      gld16(B + (size_t)(bj + row) * NB + k0 + qs * 8, &Bt[bufi][c * 16][0]);
    }
  };

  stage(0, kbase);
  __syncthreads();

  int cur = 0;
  for (int k0 = kbase; k0 < kend; k0 += 32) {
    if (k0 + 32 < kend) stage(cur ^ 1, k0 + 32);
    bf16x8 a[4], b[4];
#pragma unroll
    for (int m = 0; m < 4; ++m) {
      const int row = wr * 64 + m * 16 + fr;
      a[m] = *(const bf16x8*)((const char*)&At[cur][row][0] + ((fq ^ (row & 3)) * 16));
    }
#pragma unroll
    for (int n = 0; n < 4; ++n) {
      const int row = wc * 64 + n * 16 + fr;
      b[n] = *(const bf16x8*)((const char*)&Bt[cur][row][0] + ((fq ^ (row & 3)) * 16));
    }
#pragma unroll
    for (int m = 0; m < 4; ++m)
#pragma unroll
      for (int n = 0; n < 4; ++n)
        acc[m][n] = __builtin_amdgcn_mfma_f32_16x16x32_bf16(a[m], b[n], acc[m][n], 0, 0, 0);
    __syncthreads();
    cur ^= 1;
  }

#pragma unroll
  for (int m = 0; m < 4; ++m)
#pragma unroll
    for (int n = 0; n < 4; ++n)
#pragma unroll
      for (int r = 0; r < 4; ++r) {
        const int row = bi + wr * 64 + m * 16 + fq * 4 + r;
        const int col = bj + wc * 64 + n * 16 + fr;
        C[(size_t)kz * ((size_t)NB * FD) + (size_t)row * FD + col] = f2bf(acc[m][n][r]);
      }
}

// ---------------- NT bf16 MFMA GEMM, 2-phase dbuf + XCD swizzle -------------
// EPI: 0 fp32*alpha | 1 bf16*alpha | 5 splitK fp32 partial | 6 splitK bf16
template <int BM, int BN, int EPI>
__global__ __launch_bounds__(256) void gemm_nt(
    const ushort* __restrict__ A, int lda,
    const ushort* __restrict__ B, int ldb,
    void* __restrict__ Cp, int ldc, int K, float alpha,
    size_t pstride) {
  constexpr int WAVES_N = (BM <= 32) ? 4 : 2;
  constexpr int WAVES_M = 4 / WAVES_N;
  constexpr int WM = BM / WAVES_M, WN = BN / WAVES_N;
  constexpr int MR = WM / 16, NR = WN / 16;
  __shared__ __align__(16) ushort At[2][BM][32];
  __shared__ __align__(16) ushort Bt[2][BN][32];
  const int tid = threadIdx.x;
  const int wave = tid >> 6, lane = tid & 63;
  const int wr = wave / WAVES_N, wc = wave % WAVES_N;

  const int gx = gridDim.x, gy = gridDim.y;
  const int nwg = gx * gy * gridDim.z;
  int flat = blockIdx.x + gx * (blockIdx.y + gy * blockIdx.z);
  if ((nwg & 7) == 0) flat = (flat & 7) * (nwg >> 3) + (flat >> 3);
  const int bx = flat % gx, by = (flat / gx) % gy, bz = flat / (gx * gy);

  const int bi = by * BM, bj = bx * BN;
  const int fr = lane & 15, fq = lane >> 4;
  const int sub = lane >> 2, q = lane & 3;

  f32x4 acc[MR][NR];
#pragma unroll
  for (int m = 0; m < MR; ++m)
#pragma unroll
    for (int n = 0; n < NR; ++n) acc[m][n] = (f32x4){0.f, 0.f, 0.f, 0.f};

  const int kbase = (EPI >= 5) ? bz * K : 0;
  const int kend = kbase + K;

  auto stage = [&](int bufi, int k0) {
    for (int c = wave; c < BM / 16; c += 4) {
      const int row = c * 16 + sub;
      const int qs = q ^ (row & 3);
      gld16(A + (size_t)(bi + row) * lda + k0 + qs * 8, &At[bufi][c * 16][0]);
    }
    for (int c = wave; c < BN / 16; c += 4) {
      const int row = c * 16 + sub;
      const int qs = q ^ (row & 3);
      gld16(B + (size_t)(bj + row) * ldb + k0 + qs * 8, &Bt[bufi][c * 16][0]);
    }
  };

  stage(0, kbase);
  __syncthreads();

  int cur = 0;
  for (int k0 = kbase; k0 < kend; k0 += 32) {
    if (k0 + 32 < kend) stage(cur ^ 1, k0 + 32);
    bf16x8 a[MR], b[NR];
#pragma unroll
    for (int m = 0; m < MR; ++m) {
      const int row = wr * WM + m * 16 + fr;
      a[m] = *(const bf16x8*)((const char*)&At[cur][row][0] + ((fq ^ (row & 3)) * 16));
    }
#pragma unroll
    for (int n = 0; n < NR; ++n) {
      const int row = wc * WN + n * 16 + fr;
      b[n] = *(const bf16x8*)((const char*)&Bt[cur][row][0] + ((fq ^ (row & 3)) * 16));
    }
#pragma unroll
    for (int m = 0; m < MR; ++m)
#pragma unroll
      for (int n = 0; n < NR; ++n)
        acc[m][n] = __builtin_amdgcn_mfma_f32_16x16x32_bf16(a[m], b[n], acc[m][n], 0, 0, 0);
    __syncthreads();
    cur ^= 1;
  }

#pragma unroll
  for (int m = 0; m < MR; ++m)
#pragma unroll
    for (int n = 0; n < NR; ++n)
#pragma unroll
      for (int r = 0; r < 4; ++r) {
        const int row = bi + wr * WM + m * 16 + fq * 4 + r;
        const int col = bj + wc * WN + n * 16 + fr;
        const size_t ci = (size_t)row * ldc + col;
        const float v = acc[m][n][r];
        if (EPI == 0) ((float*)Cp)[ci] = v * alpha;
        else if (EPI == 1) ((ushort*)Cp)[ci] = f2bf(v * alpha);
        else if (EPI == 5) ((float*)Cp)[(size_t)bz * pstride + ci] = v;
        else if (EPI == 6) ((ushort*)Cp)[(size_t)bz * pstride + ci] = f2bf(v);
      }
}

// ---------------------------------------------------------------------------
extern "C" void kernel_launch(void* const* d_in, const int* in_sizes, int n_in,
                              void* d_out, int out_size, void* d_ws, size_t ws_size,
                              hipStream_t stream) {
  const float* h      = (const float*)d_in[0];
  const float* x      = (const float*)d_in[1];
  const float* w_k    = (const float*)d_in[2];
  const float* w_q    = (const float*)d_in[3];
  const float* w_v    = (const float*)d_in[4];
  const float* mixing = (const float*)d_in[5];
  const float* gamma  = (const float*)d_in[6];
  const float* beta   = (const float*)d_in[7];

  float* out_h = (float*)d_out;
  float* out_x = out_h + (size_t)NB * FD;

  char* w = (char*)d_ws;
  ushort* S     = (ushort*)(w + 0);           // 32MB bf16 scores
  ushort* P     = (ushort*)(w + 33554432);    // 32MB
  ushort* PT    = (ushort*)(w + 67108864);    // 32MB
  ushort* hnb   = (ushort*)(w + 100663296);   // 2MB
  ushort* xnb   = (ushort*)(w + 102760448);   // 2MB
  ushort* xnbT  = (ushort*)(w + 104857600);   // 2MB  [256][NB] (stack base)
  ushort* hnbT  = (ushort*)(w + 106954752);   // 2MB  [256][NB] (stack rows 256-511)
  ushort* kq    = (ushort*)(w + 109051904);   // 4MB  [NB][512]
  ushort* hvT   = (ushort*)(w + 113246208);   // 2MB  [256][NB]
  float*  t23   = (float*)(w + 115343360);    // 8MB  [NB][512]
  ushort* t23B  = (ushort*)(w + 123731968);   // 256KB [512][256] (G | Bv)
  ushort* M2T   = (ushort*)(w + 123994112);   // 128KB
  ushort* wkqb  = (ushort*)(w + 124125184);   // 256KB [512][256]
  ushort* wvAb  = (ushort*)(w + 124387328);   // 128KB
  float*  wvbT3 = (float*)(w + 124518400);    // 3KB
  float*  diag  = (float*)(w + 124521472);    // 16KB
  float*  sv    = (float*)(w + 124537856);    // 1KB
  // aliases (disjoint lifetimes):
  float*  Gramp = (float*)(w + 67108864);     // 8MB in PT region (dead before PT)
  ushort* px    = (ushort*)(w + 0);           // 8MB in S region (S dead after softmax)
  ushort* ph    = (ushort*)(w + 16777216);    // 8MB

  rownorm_wcast_kernel<<<NB + FD, 256, 0, stream>>>(
      h, x, gamma, beta, hnb, xnb, diag, w_k, w_q, w_v, wkqb, wvAb, wvbT3);
  transpose2_kernel<<<dim3(FD / 64, NB / 64, 2), 256, 0, stream>>>(
      xnb, xnbT, hnb, hnbT, NB, FD);
  colsum_kernel<<<FD, 256, 0, stream>>>(xnbT, sv);

  // batched: kq = hn @ [w_k;w_q]^T | Gram stacked (split-K 16) | hvT = w_vA @ hn^T
  {
    GDesc dkq = {hnb, wkqb, kq, FD, FD, 512, FD, 8, 64, 1, 1.f, 0, 512};
    GDesc dgr = {xnbT, xnbT, Gramp, NB, NB, 512, NB / 16, 8, 4, 5, 1.f,
                 (long)(256 * 512), 512};
    GDesc dhv = {wvAb, hnb, hvT, FD, FD, NB, FD, 64, 4, 1, 1.f, 0, 256};
    gemm_batch3<<<1280, 256, 0, stream>>>(dkq, dgr, dhv, 1280);
  }
  reduce16g_kernel<<<256 * 512 / 256, 256, 0, stream>>>(Gramp, t23B, M2T);

  // Bv = w_vA @ M2 (via M2T)
  gemm_nt<64, 64, 1><<<dim3(4, 4), 256, 0, stream>>>(
      wvAb, FD, M2T, FD, t23B + 256 * 256, FD, FD, 1.f, 0);

  // t23 = xn @ [G; Bv]^T -> [NB, 512] fp32
  gemm_nt<64, 64, 0><<<dim3(512 / 64, NB / 64), 256, 0, stream>>>(
      xnb, FD, t23B, FD, t23, 512, FD, 1.f, 0);

  // S = bf16((k @ q^T) / 16)
  gemm_nt<128, 128, 1><<<dim3(NB / 128, NB / 128), 256, 0, stream>>>(
      kq, 512, kq + 256, 512, S, NB, FD, 0.0625f, 0);

  // softmax: S -> P ; vectorized transpose: P -> PT
  softmax_kernel<<<NB, 256, 0, stream>>>(S, P);
  transpose4_kernel<<<dim3(NB / 64, NB / 64), 256, 0, stream>>>(P, PT, NB, NB);

  // merged aggregation partials: 128x128 tiles, split-K 4, both GEMMs
  gemm_agg<<<dim3(2, 32, 8), 256, 0, stream>>>(P, PT, xnbT, hvT, px, ph);

  // mega combine -> out_x, out_h
  megacombine_kernel<<<NB, 256, 0, stream>>>(
      px, ph, t23, xnb, sv, diag, x, h, wvbT3, mixing, out_x, out_h);
}

// Round 13
// 117.659 us; speedup vs baseline: 1.4279x; 1.0491x over previous
//
#include <hip/hip_runtime.h>
#include <cstdint>
#include <cstddef>

#define NB 4096
#define FD 256

typedef __attribute__((ext_vector_type(4))) float f32x4;
typedef __attribute__((ext_vector_type(8))) short bf16x8;

__device__ __forceinline__ ushort f2bf(float f) {
  union { float f; uint32_t u; } v; v.f = f;
  uint32_t r = v.u + 0x7fffu + ((v.u >> 16) & 1u);
  return (ushort)(r >> 16);
}
__device__ __forceinline__ float bf2f(ushort b) {
  union { uint32_t u; float f; } v; v.u = ((uint32_t)b) << 16;
  return v.f;
}

__device__ __forceinline__ void gld16(const void* g, void* l) {
  __builtin_amdgcn_global_load_lds(
      (const __attribute__((address_space(1))) char*)g,
      (__attribute__((address_space(3))) char*)l, 16, 0, 0);
}

__device__ __forceinline__ float wave_reduce_sum(float v) {
#pragma unroll
  for (int off = 32; off >= 1; off >>= 1) v += __shfl_xor(v, off);
  return v;
}
__device__ __forceinline__ float wave_reduce_max(float v) {
#pragma unroll
  for (int off = 32; off >= 1; off >>= 1) v = fmaxf(v, __shfl_xor(v, off));
  return v;
}

// ---------------- rownorm + weight casts (merged) ---------------------------
__global__ __launch_bounds__(256) void rownorm_wcast_kernel(
    const float* __restrict__ h, const float* __restrict__ x,
    const float* __restrict__ gamma, const float* __restrict__ beta,
    ushort* __restrict__ hnb, ushort* __restrict__ xnb, float* __restrict__ diag,
    const float* __restrict__ w_k, const float* __restrict__ w_q,
    const float* __restrict__ w_v,
    ushort* __restrict__ wkqb, ushort* __restrict__ wvAb,
    float* __restrict__ wvbT3) {
  __shared__ float rA[4], rB[4], rC[4], rD[4];
  if (blockIdx.x >= NB) {
    const int r = blockIdx.x - NB, t = threadIdx.x;
    wkqb[r * 256 + t] = f2bf(w_k[r * 256 + t]);
    wkqb[(256 + r) * 256 + t] = f2bf(w_q[r * 256 + t]);
    wvAb[r * 256 + t] = f2bf(w_v[(size_t)r * 259 + t]);
    if (t < 3) wvbT3[t * 256 + r] = w_v[(size_t)r * 259 + 256 + t];
    return;
  }
  const int r = blockIdx.x, t = threadIdx.x, wid = t >> 6, lane = t & 63;
  const size_t base = (size_t)r * FD + t;
  const float hv = h[base], xv = x[base];
  float s1 = wave_reduce_sum(hv);
  float s2 = wave_reduce_sum(hv * hv);
  float a1 = wave_reduce_sum(fabsf(xv));
  float q1 = wave_reduce_sum(xv * xv);
  if (lane == 0) { rA[wid] = s1; rB[wid] = s2; rC[wid] = a1; rD[wid] = q1; }
  __syncthreads();
  const float S1 = rA[0] + rA[1] + rA[2] + rA[3];
  const float S2 = rB[0] + rB[1] + rB[2] + rB[3];
  const float L1 = rC[0] + rC[1] + rC[2] + rC[3];
  const float Q1 = rD[0] + rD[1] + rD[2] + rD[3];
  const float mu = S1 * (1.0f / FD);
  const float var = S2 * (1.0f / FD) - mu * mu;
  const float rstd = rsqrtf(var + 1e-5f);
  const float d = fmaxf(L1, 1e-12f), dinv = 1.0f / d;
  hnb[base] = f2bf((hv - mu) * rstd * gamma[t] + beta[t]);
  xnb[base] = f2bf(xv * dinv);
  if (t == 0) diag[r] = Q1 * dinv * dinv;
}

// ---------------- bf16 transpose (64x64 tiles); z selects src/dst pair ------
__global__ __launch_bounds__(256) void transpose2_kernel(
    const ushort* __restrict__ inA, ushort* __restrict__ outA,
    const ushort* __restrict__ inB, ushort* __restrict__ outB, int R, int C) {
  __shared__ ushort tile[64][65];
  const ushort* in = blockIdx.z ? inB : inA;
  ushort* out = blockIdx.z ? outB : outA;
  const int bc = blockIdx.x * 64, br = blockIdx.y * 64;
  const int t = threadIdx.x;
#pragma unroll
  for (int i = 0; i < 16; ++i) {
    const int idx = t + 256 * i;
    const int rr = idx >> 6, cc = idx & 63;
    tile[rr][cc] = in[(size_t)(br + rr) * C + bc + cc];
  }
  __syncthreads();
#pragma unroll
  for (int i = 0; i < 16; ++i) {
    const int idx = t + 256 * i;
    const int rr = idx >> 6, cc = idx & 63;
    out[(size_t)(bc + rr) * R + br + cc] = tile[cc][rr];
  }
}

// ---------------- vectorized bf16 transpose (ushort4 both global sides) -----
__global__ __launch_bounds__(256) void transpose4_kernel(
    const ushort* __restrict__ in, ushort* __restrict__ out, int R, int C) {
  __shared__ ushort tile[64][66];
  const int bc = blockIdx.x * 64, br = blockIdx.y * 64;
  const int t = threadIdx.x;
  const int c4 = (t & 15) * 4;
  const int r0 = t >> 4;
#pragma unroll
  for (int i = 0; i < 4; ++i) {
    const int rr = r0 + 16 * i;
    *(ushort4*)&tile[rr][c4] =
        *(const ushort4*)(in + (size_t)(br + rr) * C + bc + c4);
  }
  __syncthreads();
#pragma unroll
  for (int i = 0; i < 4; ++i) {
    const int ro = r0 + 16 * i;
    ushort4 o;
    o.x = tile[c4 + 0][ro];
    o.y = tile[c4 + 1][ro];
    o.z = tile[c4 + 2][ro];
    o.w = tile[c4 + 3][ro];
    *(ushort4*)(out + (size_t)(bc + ro) * R + br + c4) = o;
  }
}

// ---------------- colsum of xn ----------------------------------------------
__global__ __launch_bounds__(256) void colsum_kernel(
    const ushort* __restrict__ xnT, float* __restrict__ s) {
  __shared__ float red[4];
  const int f = blockIdx.x, t = threadIdx.x, wid = t >> 6, lane = t & 63;
  float a = 0.f;
#pragma unroll
  for (int i = 0; i < 16; ++i) a += bf2f(xnT[(size_t)f * NB + t + 256 * i]);
  a = wave_reduce_sum(a);
  if (lane == 0) red[wid] = a;
  __syncthreads();
  if (t == 0) s[f] = red[0] + red[1] + red[2] + red[3];
}

// ---------------- Gram split-K reduce: [16][256][512] -> G | M2T ------------
__global__ __launch_bounds__(256) void reduce16g_kernel(
    const float* __restrict__ in, ushort* __restrict__ t23B,
    ushort* __restrict__ M2T) {
  const int idx = blockIdx.x * 256 + threadIdx.x;
  const int i = idx >> 9, j = idx & 511;
  float a = 0.f;
#pragma unroll
  for (int z = 0; z < 16; ++z) a += in[(size_t)z * (256 * 512) + idx];
  if (j < 256) t23B[i * 256 + j] = f2bf(a);
  else M2T[i * 256 + (j - 256)] = f2bf(a);
}

// ---------------- row softmax: S bf16 -> P bf16 -----------------------------
__global__ __launch_bounds__(256) void softmax_kernel(
    const ushort* __restrict__ S, ushort* __restrict__ P) {
  __shared__ float red[4];
  const int r = blockIdx.x, t = threadIdx.x, wid = t >> 6, lane = t & 63;
  const uint4* Sr = (const uint4*)(S + (size_t)r * NB);
  float v[16];
  float lmax = -1e30f;
#pragma unroll
  for (int i = 0; i < 2; ++i) {
    const uint4 c = Sr[t + 256 * i];
    const uint32_t w4[4] = {c.x, c.y, c.z, c.w};
#pragma unroll
    for (int j = 0; j < 4; ++j) {
      v[i * 8 + j * 2]     = bf2f((ushort)(w4[j] & 0xffffu));
      v[i * 8 + j * 2 + 1] = bf2f((ushort)(w4[j] >> 16));
    }
  }
#pragma unroll
  for (int u = 0; u < 16; ++u) lmax = fmaxf(lmax, v[u]);
  lmax = wave_reduce_max(lmax);
  if (lane == 0) red[wid] = lmax;
  __syncthreads();
  const float gmax = fmaxf(fmaxf(red[0], red[1]), fmaxf(red[2], red[3]));
  __syncthreads();
  float lsum = 0.f;
#pragma unroll
  for (int u = 0; u < 16; ++u) { v[u] = __expf(v[u] - gmax); lsum += v[u]; }
  lsum = wave_reduce_sum(lsum);
  if (lane == 0) red[wid] = lsum;
  __syncthreads();
  const float pinv = 1.f / (red[0] + red[1] + red[2] + red[3]);
  uint4* Pr = (uint4*)(P + (size_t)r * NB);
#pragma unroll
  for (int i = 0; i < 2; ++i) {
    uint4 o;
    o.x = (uint32_t)f2bf(v[i*8+0] * pinv) | ((uint32_t)f2bf(v[i*8+1] * pinv) << 16);
    o.y = (uint32_t)f2bf(v[i*8+2] * pinv) | ((uint32_t)f2bf(v[i*8+3] * pinv) << 16);
    o.z = (uint32_t)f2bf(v[i*8+4] * pinv) | ((uint32_t)f2bf(v[i*8+5] * pinv) << 16);
    o.w = (uint32_t)f2bf(v[i*8+6] * pinv) | ((uint32_t)f2bf(v[i*8+7] * pinv) << 16);
    Pr[t + 256 * i] = o;
  }
}

// ---------------- mega combine: both outputs --------------------------------
__global__ __launch_bounds__(256) void megacombine_kernel(
    const ushort* __restrict__ px, const ushort* __restrict__ ph,
    const float* __restrict__ t23, const ushort* __restrict__ xnb,
    const float* __restrict__ sv, const float* __restrict__ diag,
    const float* __restrict__ x, const float* __restrict__ h,
    const float* __restrict__ wvbT3, const float* __restrict__ mix,
    float* __restrict__ out_x, float* __restrict__ out_h) {
  __shared__ float rA[4], rB[4];
  const size_t NF = (size_t)NB * FD;
  const int i = blockIdx.x, f = threadIdx.x, wid = f >> 6, lane = f & 63;
  const float e0x = __expf(mix[0]), e1x = __expf(mix[2]);
  const float mAx = e0x / (e0x + e1x), mBx = e1x / (e0x + e1x);
  const float e0h = __expf(mix[1]), e1h = __expf(mix[3]);
  const float mAh = e0h / (e0h + e1h), mBh = e1h / (e0h + e1h);

  const size_t rowoff = (size_t)i * FD + f;
  float ax = 0.f, ah = 0.f;
#pragma unroll
  for (int z = 0; z < 4; ++z) {
    ax += bf2f(px[(size_t)z * NF + rowoff]);
    ah += bf2f(ph[(size_t)z * NF + rowoff]);
  }
  const float t2v = t23[(size_t)i * 512 + f];
  const float t3v = t23[(size_t)i * 512 + 256 + f];
  const float xv = bf2f(xnb[rowoff]);

  float rs = wave_reduce_sum(xv * sv[f]);
  float rq = wave_reduce_sum(xv * t2v);
  if (lane == 0) { rA[wid] = rs; rB[wid] = rq; }
  __syncthreads();
  rs = rA[0] + rA[1] + rA[2] + rA[3];
  rq = rB[0] + rB[1] + rB[2] + rB[3];
  const float mean = rs * (1.0f / NB);
  const float var = (rq - (float)NB * mean * mean) * (1.0f / (NB - 1));
  const float sd = sqrtf(fmaxf(var, 0.f));
  const float dg = diag[i];
  const float statsterm = dg * wvbT3[f] + rs * wvbT3[256 + f] + sd * wvbT3[512 + f];

  out_x[rowoff] = mBx * ax + mAx * t2v + x[rowoff];
  const float pre = mBh * ah + mAh * t3v + statsterm;
  out_h[rowoff] = ((pre > 0.f) ? pre : expm1f(pre)) + h[rowoff];
}

// ---------------- batched 64x64 NT GEMM (3 slices, runtime descriptors) -----
struct GDesc {
  const ushort* A; const ushort* B; void* C;
  int lda, ldb, ldc, K, gx, gy, epi;   // epi: 1 bf16 store, 5 splitK fp32
  float alpha; long pstride; int nb;
};

__global__ __launch_bounds__(256) void gemm_batch3(
    GDesc d0, GDesc d1, GDesc d2, int ntot) {
  int flat = blockIdx.x;
  flat = (flat & 7) * (ntot >> 3) + (flat >> 3);
  GDesc d; int l;
  if (flat < d0.nb) { d = d0; l = flat; }
  else if (flat < d0.nb + d1.nb) { d = d1; l = flat - d0.nb; }
  else { d = d2; l = flat - d0.nb - d1.nb; }
  const int bx = l % d.gx;
  const int rest = l / d.gx;
  const int by = rest % d.gy, bz = rest / d.gy;

  __shared__ __align__(16) ushort At[2][64][32];
  __shared__ __align__(16) ushort Bt[2][64][32];
  const int tid = threadIdx.x;
  const int wave = tid >> 6, lane = tid & 63;
  const int wr = wave >> 1, wc = wave & 1;
  const int bi = by * 64, bj = bx * 64;
  const int fr = lane & 15, fq = lane >> 4;
  const int sub = lane >> 2, q = lane & 3;

  f32x4 acc[2][2];
#pragma unroll
  for (int m = 0; m < 2; ++m)
#pragma unroll
    for (int n = 0; n < 2; ++n) acc[m][n] = (f32x4){0.f, 0.f, 0.f, 0.f};

  const int kbase = bz * d.K;
  const int kend = kbase + d.K;

  auto stage = [&](int bufi, int k0) {
    {
      const int row = wave * 16 + sub;
      const int qs = q ^ (row & 3);
      gld16(d.A + (size_t)(bi + row) * d.lda + k0 + qs * 8, &At[bufi][wave * 16][0]);
    }
    {
      const int row = wave * 16 + sub;
      const int qs = q ^ (row & 3);
      gld16(d.B + (size_t)(bj + row) * d.ldb + k0 + qs * 8, &Bt[bufi][wave * 16][0]);
    }
  };

  stage(0, kbase);
  __syncthreads();

  int cur = 0;
  for (int k0 = kbase; k0 < kend; k0 += 32) {
    if (k0 + 32 < kend) stage(cur ^ 1, k0 + 32);
    bf16x8 a[2], b[2];
#pragma unroll
    for (int m = 0; m < 2; ++m) {
      const int row = wr * 32 + m * 16 + fr;
      a[m] = *(const bf16x8*)((const char*)&At[cur][row][0] + ((fq ^ (row & 3)) * 16));
    }
#pragma unroll
    for (int n = 0; n < 2; ++n) {
      const int row = wc * 32 + n * 16 + fr;
      b[n] = *(const bf16x8*)((const char*)&Bt[cur][row][0] + ((fq ^ (row & 3)) * 16));
    }
#pragma unroll
    for (int m = 0; m < 2; ++m)
#pragma unroll
      for (int n = 0; n < 2; ++n)
        acc[m][n] = __builtin_amdgcn_mfma_f32_16x16x32_bf16(a[m], b[n], acc[m][n], 0, 0, 0);
    __syncthreads();
    cur ^= 1;
  }

#pragma unroll
  for (int m = 0; m < 2; ++m)
#pragma unroll
    for (int n = 0; n < 2; ++n)
#pragma unroll
      for (int r = 0; r < 4; ++r) {
        const int row = bi + wr * 32 + m * 16 + fq * 4 + r;
        const int col = bj + wc * 32 + n * 16 + fr;
        const size_t ci = (size_t)row * d.ldc + col;
        const float v = acc[m][n][r];
        if (d.epi == 1) ((ushort*)d.C)[ci] = f2bf(v * d.alpha);
        else ((float*)d.C)[(size_t)bz * d.pstride + ci] = v;
      }
}

// ---------------- 128x128 BK=64 core (shared by agg and batch2) -------------
// Stage swizzle: 128B rows = 32 banks, so chunk (3-bit) is XORed with row&7
// on BOTH the global source and the ds_read side (both-sides rule).
#define GEMM128_BODY(APTR, BPTR, LDA, LDB, KBASE, KEND)                        \
  f32x4 acc[4][4];                                                             \
  _Pragma("unroll") for (int m = 0; m < 4; ++m)                                \
      _Pragma("unroll") for (int n = 0; n < 4; ++n)                            \
          acc[m][n] = (f32x4){0.f, 0.f, 0.f, 0.f};                             \
  auto stage = [&](int bufi, int k0) {                                         \
    for (int c = wave; c < 16; c += 4) {                                       \
      const int row = c * 8 + sub8;                                            \
      const int qs = q8 ^ (row & 7);                                           \
      gld16(APTR + (size_t)(bi + row) * LDA + k0 + qs * 8, &At[bufi][c * 8][0]); \
    }                                                                          \
    for (int c = wave; c < 16; c += 4) {                                       \
      const int row = c * 8 + sub8;                                            \
      const int qs = q8 ^ (row & 7);                                           \
      gld16(BPTR + (size_t)(bj + row) * LDB + k0 + qs * 8, &Bt[bufi][c * 8][0]); \
    }                                                                          \
  };                                                                           \
  stage(0, KBASE);                                                             \
  __syncthreads();                                                             \
  int cur = 0;                                                                 \
  for (int k0 = KBASE; k0 < KEND; k0 += 64) {                                  \
    if (k0 + 64 < KEND) stage(cur ^ 1, k0 + 64);                               \
    _Pragma("unroll") for (int ks = 0; ks < 2; ++ks) {                         \
      bf16x8 a[4], b[4];                                                       \
      _Pragma("unroll") for (int m = 0; m < 4; ++m) {                          \
        const int row = wr * 64 + m * 16 + fr;                                 \
        const int ch = (ks * 4 + fq) ^ (row & 7);                              \
        a[m] = *(const bf16x8*)((const char*)&At[cur][row][0] + ch * 16);      \
      }                                                                        \
      _Pragma("unroll") for (int n = 0; n < 4; ++n) {                          \
        const int row = wc * 64 + n * 16 + fr;                                 \
        const int ch = (ks * 4 + fq) ^ (row & 7);                              \
        b[n] = *(const bf16x8*)((const char*)&Bt[cur][row][0] + ch * 16);      \
      }                                                                        \
      _Pragma("unroll") for (int m = 0; m < 4; ++m)                            \
          _Pragma("unroll") for (int n = 0; n < 4; ++n)                        \
              acc[m][n] = __builtin_amdgcn_mfma_f32_16x16x32_bf16(             \
                  a[m], b[n], acc[m][n], 0, 0, 0);                             \
    }                                                                          \
    __syncthreads();                                                           \
    cur ^= 1;                                                                  \
  }

// ---------------- merged aggregation GEMM (BK=64): P@xnT and PT@hvT ---------
// grid (2, 32, 8): z<4 -> px[z] = (P @ xnT)[kchunk z]; z>=4 -> ph[z-4].
__global__ __launch_bounds__(256) void gemm_agg(
    const ushort* __restrict__ P, const ushort* __restrict__ PT,
    const ushort* __restrict__ xnT, const ushort* __restrict__ hvT,
    ushort* __restrict__ px, ushort* __restrict__ ph) {
  __shared__ __align__(16) ushort At[2][128][64];
  __shared__ __align__(16) ushort Bt[2][128][64];
  const int tid = threadIdx.x;
  const int wave = tid >> 6, lane = tid & 63;
  const int wr = wave >> 1, wc = wave & 1;

  const int nwg = 512;
  int flat = blockIdx.x + 2 * (blockIdx.y + 32 * blockIdx.z);
  flat = (flat & 7) * (nwg >> 3) + (flat >> 3);
  const int bx = flat % 2, by = (flat / 2) % 32, bz = flat / 64;
  const int sel = bz >> 2, kz = bz & 3;

  const ushort* A = sel ? PT : P;
  const ushort* B = sel ? hvT : xnT;
  ushort* C = sel ? ph : px;

  const int bi = by * 128, bj = bx * 128;
  const int fr = lane & 15, fq = lane >> 4;
  const int sub8 = lane >> 3, q8 = lane & 7;

  const int kbase = kz * 1024;
  const int kend = kbase + 1024;

  GEMM128_BODY(A, B, NB, NB, kbase, kend)

#pragma unroll
  for (int m = 0; m < 4; ++m)
#pragma unroll
    for (int n = 0; n < 4; ++n)
#pragma unroll
      for (int r = 0; r < 4; ++r) {
        const int row = bi + wr * 64 + m * 16 + fq * 4 + r;
        const int col = bj + wc * 64 + n * 16 + fr;
        C[(size_t)kz * ((size_t)NB * FD) + (size_t)row * FD + col] = f2bf(acc[m][n][r]);
      }
}

// ---------------- batched 128x128 BK=64 GEMM: S-GEMM + t23 ------------------
struct GD2 {
  const ushort* A; const ushort* B; void* C;
  int lda, ldb, ldc, K, gx, epi;   // epi: 0 fp32, 1 bf16*alpha
  float alpha; int nb;
};

__global__ __launch_bounds__(256) void gemm_batch2big(GD2 d0, GD2 d1, int ntot) {
  __shared__ __align__(16) ushort At[2][128][64];
  __shared__ __align__(16) ushort Bt[2][128][64];
  const int tid = threadIdx.x;
  const int wave = tid >> 6, lane = tid & 63;
  const int wr = wave >> 1, wc = wave & 1;

  int flat = blockIdx.x;
  flat = (flat & 7) * (ntot >> 3) + (flat >> 3);
  GD2 d; int l;
  if (flat < d0.nb) { d = d0; l = flat; }
  else { d = d1; l = flat - d0.nb; }
  const int bx = l % d.gx, by = l / d.gx;

  const int bi = by * 128, bj = bx * 128;
  const int fr = lane & 15, fq = lane >> 4;
  const int sub8 = lane >> 3, q8 = lane & 7;

  GEMM128_BODY(d.A, d.B, d.lda, d.ldb, 0, d.K)

#pragma unroll
  for (int m = 0; m < 4; ++m)
#pragma unroll
    for (int n = 0; n < 4; ++n)
#pragma unroll
      for (int r = 0; r < 4; ++r) {
        const int row = bi + wr * 64 + m * 16 + fq * 4 + r;
        const int col = bj + wc * 64 + n * 16 + fr;
        const size_t ci = (size_t)row * d.ldc + col;
        const float v = acc[m][n][r];
        if (d.epi == 1) ((ushort*)d.C)[ci] = f2bf(v * d.alpha);
        else ((float*)d.C)[ci] = v;
      }
}

// ---------------- NT bf16 MFMA GEMM (64² small, for Bv) ---------------------
template <int BM, int BN, int EPI>
__global__ __launch_bounds__(256) void gemm_nt(
    const ushort* __restrict__ A, int lda,
    const ushort* __restrict__ B, int ldb,
    void* __restrict__ Cp, int ldc, int K, float alpha,
    size_t pstride) {
  constexpr int WAVES_N = 2, WAVES_M = 2;
  constexpr int WM = BM / WAVES_M, WN = BN / WAVES_N;
  constexpr int MR = WM / 16, NR = WN / 16;
  __shared__ __align__(16) ushort At[2][BM][32];
  __shared__ __align__(16) ushort Bt[2][BN][32];
  const int tid = threadIdx.x;
  const int wave = tid >> 6, lane = tid & 63;
  const int wr = wave / WAVES_N, wc = wave % WAVES_N;

  const int bx = blockIdx.x, by = blockIdx.y;
  const int bi = by * BM, bj = bx * BN;
  const int fr = lane & 15, fq = lane >> 4;
  const int sub = lane >> 2, q = lane & 3;

  f32x4 acc[MR][NR];
#pragma unroll
  for (int m = 0; m < MR; ++m)
#pragma unroll
    for (int n = 0; n < NR; ++n) acc[m][n] = (f32x4){0.f, 0.f, 0.f, 0.f};

  auto stage = [&](int bufi, int k0) {
    for (int c = wave; c < BM / 16; c += 4) {
      const int row = c * 16 + sub;
      const int qs = q ^ (row & 3);
      gld16(A + (size_t)(bi + row) * lda + k0 + qs * 8, &At[bufi][c * 16][0]);
    }
    for (int c = wave; c < BN / 16; c += 4) {
      const int row = c * 16 + sub;
      const int qs = q ^ (row & 3);
      gld16(B + (size_t)(bj + row) * ldb + k0 + qs * 8, &Bt[bufi][c * 16][0]);
    }
  };

  stage(0, 0);
  __syncthreads();

  int cur = 0;
  for (int k0 = 0; k0 < K; k0 += 32) {
    if (k0 + 32 < K) stage(cur ^ 1, k0 + 32);
    bf16x8 a[MR], b[NR];
#pragma unroll
    for (int m = 0; m < MR; ++m) {
      const int row = wr * WM + m * 16 + fr;
      a[m] = *(const bf16x8*)((const char*)&At[cur][row][0] + ((fq ^ (row & 3)) * 16));
    }
#pragma unroll
    for (int n = 0; n < NR; ++n) {
      const int row = wc * WN + n * 16 + fr;
      b[n] = *(const bf16x8*)((const char*)&Bt[cur][row][0] + ((fq ^ (row & 3)) * 16));
    }
#pragma unroll
    for (int m = 0; m < MR; ++m)
#pragma unroll
      for (int n = 0; n < NR; ++n)
        acc[m][n] = __builtin_amdgcn_mfma_f32_16x16x32_bf16(a[m], b[n], acc[m][n], 0, 0, 0);
    __syncthreads();
    cur ^= 1;
  }

#pragma unroll
  for (int m = 0; m < MR; ++m)
#pragma unroll
    for (int n = 0; n < NR; ++n)
#pragma unroll
      for (int r = 0; r < 4; ++r) {
        const int row = bi + wr * WM + m * 16 + fq * 4 + r;
        const int col = bj + wc * WN + n * 16 + fr;
        const size_t ci = (size_t)row * ldc + col;
        const float v = acc[m][n][r];
        if (EPI == 0) ((float*)Cp)[ci] = v * alpha;
        else ((ushort*)Cp)[ci] = f2bf(v * alpha);
      }
}

// ---------------------------------------------------------------------------
extern "C" void kernel_launch(void* const* d_in, const int* in_sizes, int n_in,
                              void* d_out, int out_size, void* d_ws, size_t ws_size,
                              hipStream_t stream) {
  const float* h      = (const float*)d_in[0];
  const float* x      = (const float*)d_in[1];
  const float* w_k    = (const float*)d_in[2];
  const float* w_q    = (const float*)d_in[3];
  const float* w_v    = (const float*)d_in[4];
  const float* mixing = (const float*)d_in[5];
  const float* gamma  = (const float*)d_in[6];
  const float* beta   = (const float*)d_in[7];

  float* out_h = (float*)d_out;
  float* out_x = out_h + (size_t)NB * FD;

  char* w = (char*)d_ws;
  ushort* S     = (ushort*)(w + 0);           // 32MB bf16 scores
  ushort* P     = (ushort*)(w + 33554432);    // 32MB
  ushort* PT    = (ushort*)(w + 67108864);    // 32MB
  ushort* hnb   = (ushort*)(w + 100663296);   // 2MB
  ushort* xnb   = (ushort*)(w + 102760448);   // 2MB
  ushort* xnbT  = (ushort*)(w + 104857600);   // 2MB  [256][NB]
  ushort* hnbT  = (ushort*)(w + 106954752);   // 2MB  [256][NB]
  ushort* kq    = (ushort*)(w + 109051904);   // 4MB  [NB][512]
  ushort* hvT   = (ushort*)(w + 113246208);   // 2MB  [256][NB]
  float*  t23   = (float*)(w + 115343360);    // 8MB  [NB][512]
  ushort* t23B  = (ushort*)(w + 123731968);   // 256KB [512][256] (G | Bv)
  ushort* M2T   = (ushort*)(w + 123994112);   // 128KB
  ushort* wkqb  = (ushort*)(w + 124125184);   // 256KB [512][256]
  ushort* wvAb  = (ushort*)(w + 124387328);   // 128KB
  float*  wvbT3 = (float*)(w + 124518400);    // 3KB
  float*  diag  = (float*)(w + 124521472);    // 16KB
  float*  sv    = (float*)(w + 124537856);    // 1KB
  // aliases (disjoint lifetimes):
  float*  Gramp = (float*)(w + 67108864);     // 8MB in PT region (dead before PT)
  ushort* px    = (ushort*)(w + 0);           // 8MB in S region (S dead after softmax)
  ushort* ph    = (ushort*)(w + 16777216);    // 8MB

  rownorm_wcast_kernel<<<NB + FD, 256, 0, stream>>>(
      h, x, gamma, beta, hnb, xnb, diag, w_k, w_q, w_v, wkqb, wvAb, wvbT3);
  transpose2_kernel<<<dim3(FD / 64, NB / 64, 2), 256, 0, stream>>>(
      xnb, xnbT, hnb, hnbT, NB, FD);
  colsum_kernel<<<FD, 256, 0, stream>>>(xnbT, sv);

  // batched: kq = hn @ [w_k;w_q]^T | Gram stacked (split-K 16) | hvT = w_vA @ hn^T
  {
    GDesc dkq = {hnb, wkqb, kq, FD, FD, 512, FD, 8, 64, 1, 1.f, 0, 512};
    GDesc dgr = {xnbT, xnbT, Gramp, NB, NB, 512, NB / 16, 8, 4, 5, 1.f,
                 (long)(256 * 512), 512};
    GDesc dhv = {wvAb, hnb, hvT, FD, FD, NB, FD, 64, 4, 1, 1.f, 0, 256};
    gemm_batch3<<<1280, 256, 0, stream>>>(dkq, dgr, dhv, 1280);
  }
  reduce16g_kernel<<<256 * 512 / 256, 256, 0, stream>>>(Gramp, t23B, M2T);

  // Bv = w_vA @ M2 (via M2T)
  gemm_nt<64, 64, 1><<<dim3(4, 4), 256, 0, stream>>>(
      wvAb, FD, M2T, FD, t23B + 256 * 256, FD, FD, 1.f, 0);

  // batched big: S = bf16((k@q^T)/16) | t23 = xn @ [G; Bv]^T (fp32)
  {
    GD2 dS  = {kq, kq + 256, S, 512, 512, NB, FD, 32, 1, 0.0625f, 1024};
    GD2 dT  = {xnb, t23B, t23, FD, FD, 512, FD, 4, 0, 1.f, 128};
    gemm_batch2big<<<1152, 256, 0, stream>>>(dS, dT, 1152);
  }

  // softmax: S -> P ; vectorized transpose: P -> PT
  softmax_kernel<<<NB, 256, 0, stream>>>(S, P);
  transpose4_kernel<<<dim3(NB / 64, NB / 64), 256, 0, stream>>>(P, PT, NB, NB);

  // merged aggregation partials: 128x128 tiles BK=64, split-K 4, both GEMMs
  gemm_agg<<<dim3(2, 32, 8), 256, 0, stream>>>(P, PT, xnbT, hvT, px, ph);

  // mega combine -> out_x, out_h
  megacombine_kernel<<<NB, 256, 0, stream>>>(
      px, ph, t23, xnb, sv, diag, x, h, wvbT3, mixing, out_x, out_h);
}

// Round 14
// 116.828 us; speedup vs baseline: 1.4380x; 1.0071x over previous
//
#include <hip/hip_runtime.h>
#include <cstdint>
#include <cstddef>

#define NB 4096
#define FD 256

typedef __attribute__((ext_vector_type(4))) float f32x4;
typedef __attribute__((ext_vector_type(8))) short bf16x8;

__device__ __forceinline__ ushort f2bf(float f) {
  union { float f; uint32_t u; } v; v.f = f;
  uint32_t r = v.u + 0x7fffu + ((v.u >> 16) & 1u);
  return (ushort)(r >> 16);
}
__device__ __forceinline__ float bf2f(ushort b) {
  union { uint32_t u; float f; } v; v.u = ((uint32_t)b) << 16;
  return v.f;
}

__device__ __forceinline__ void gld16(const void* g, void* l) {
  __builtin_amdgcn_global_load_lds(
      (const __attribute__((address_space(1))) char*)g,
      (__attribute__((address_space(3))) char*)l, 16, 0, 0);
}

__device__ __forceinline__ float wave_reduce_sum(float v) {
#pragma unroll
  for (int off = 32; off >= 1; off >>= 1) v += __shfl_xor(v, off);
  return v;
}
__device__ __forceinline__ float wave_reduce_max(float v) {
#pragma unroll
  for (int off = 32; off >= 1; off >>= 1) v = fmaxf(v, __shfl_xor(v, off));
  return v;
}

// ---------------- rownorm + weight casts (merged) ---------------------------
__global__ __launch_bounds__(256) void rownorm_wcast_kernel(
    const float* __restrict__ h, const float* __restrict__ x,
    const float* __restrict__ gamma, const float* __restrict__ beta,
    ushort* __restrict__ hnb, ushort* __restrict__ xnb, float* __restrict__ diag,
    const float* __restrict__ w_k, const float* __restrict__ w_q,
    const float* __restrict__ w_v,
    ushort* __restrict__ wkqb, ushort* __restrict__ wvAb,
    float* __restrict__ wvbT3) {
  __shared__ float rA[4], rB[4], rC[4], rD[4];
  if (blockIdx.x >= NB) {
    const int r = blockIdx.x - NB, t = threadIdx.x;
    wkqb[r * 256 + t] = f2bf(w_k[r * 256 + t]);
    wkqb[(256 + r) * 256 + t] = f2bf(w_q[r * 256 + t]);
    wvAb[r * 256 + t] = f2bf(w_v[(size_t)r * 259 + t]);
    if (t < 3) wvbT3[t * 256 + r] = w_v[(size_t)r * 259 + 256 + t];
    return;
  }
  const int r = blockIdx.x, t = threadIdx.x, wid = t >> 6, lane = t & 63;
  const size_t base = (size_t)r * FD + t;
  const float hv = h[base], xv = x[base];
  float s1 = wave_reduce_sum(hv);
  float s2 = wave_reduce_sum(hv * hv);
  float a1 = wave_reduce_sum(fabsf(xv));
  float q1 = wave_reduce_sum(xv * xv);
  if (lane == 0) { rA[wid] = s1; rB[wid] = s2; rC[wid] = a1; rD[wid] = q1; }
  __syncthreads();
  const float S1 = rA[0] + rA[1] + rA[2] + rA[3];
  const float S2 = rB[0] + rB[1] + rB[2] + rB[3];
  const float L1 = rC[0] + rC[1] + rC[2] + rC[3];
  const float Q1 = rD[0] + rD[1] + rD[2] + rD[3];
  const float mu = S1 * (1.0f / FD);
  const float var = S2 * (1.0f / FD) - mu * mu;
  const float rstd = rsqrtf(var + 1e-5f);
  const float d = fmaxf(L1, 1e-12f), dinv = 1.0f / d;
  hnb[base] = f2bf((hv - mu) * rstd * gamma[t] + beta[t]);
  xnb[base] = f2bf(xv * dinv);
  if (t == 0) diag[r] = Q1 * dinv * dinv;
}

// ---------------- bf16 transpose (64x64 tiles); z selects src/dst pair ------
__global__ __launch_bounds__(256) void transpose2_kernel(
    const ushort* __restrict__ inA, ushort* __restrict__ outA,
    const ushort* __restrict__ inB, ushort* __restrict__ outB, int R, int C) {
  __shared__ ushort tile[64][65];
  const ushort* in = blockIdx.z ? inB : inA;
  ushort* out = blockIdx.z ? outB : outA;
  const int bc = blockIdx.x * 64, br = blockIdx.y * 64;
  const int t = threadIdx.x;
#pragma unroll
  for (int i = 0; i < 16; ++i) {
    const int idx = t + 256 * i;
    const int rr = idx >> 6, cc = idx & 63;
    tile[rr][cc] = in[(size_t)(br + rr) * C + bc + cc];
  }
  __syncthreads();
#pragma unroll
  for (int i = 0; i < 16; ++i) {
    const int idx = t + 256 * i;
    const int rr = idx >> 6, cc = idx & 63;
    out[(size_t)(bc + rr) * R + br + cc] = tile[cc][rr];
  }
}

// ---------------- vectorized bf16 transpose (ushort4 both global sides) -----
__global__ __launch_bounds__(256) void transpose4_kernel(
    const ushort* __restrict__ in, ushort* __restrict__ out, int R, int C) {
  __shared__ ushort tile[64][66];
  const int bc = blockIdx.x * 64, br = blockIdx.y * 64;
  const int t = threadIdx.x;
  const int c4 = (t & 15) * 4;
  const int r0 = t >> 4;
#pragma unroll
  for (int i = 0; i < 4; ++i) {
    const int rr = r0 + 16 * i;
    *(ushort4*)&tile[rr][c4] =
        *(const ushort4*)(in + (size_t)(br + rr) * C + bc + c4);
  }
  __syncthreads();
#pragma unroll
  for (int i = 0; i < 4; ++i) {
    const int ro = r0 + 16 * i;
    ushort4 o;
    o.x = tile[c4 + 0][ro];
    o.y = tile[c4 + 1][ro];
    o.z = tile[c4 + 2][ro];
    o.w = tile[c4 + 3][ro];
    *(ushort4*)(out + (size_t)(bc + ro) * R + br + c4) = o;
  }
}

// ---------------- Gram split-K reduce: [16][256][512] -> G | M2T ------------
__global__ __launch_bounds__(256) void reduce16g_kernel(
    const float* __restrict__ in, ushort* __restrict__ t23B,
    ushort* __restrict__ M2T) {
  const int idx = blockIdx.x * 256 + threadIdx.x;
  const int i = idx >> 9, j = idx & 511;
  float a = 0.f;
#pragma unroll
  for (int z = 0; z < 16; ++z) a += in[(size_t)z * (256 * 512) + idx];
  if (j < 256) t23B[i * 256 + j] = f2bf(a);
  else M2T[i * 256 + (j - 256)] = f2bf(a);
}

// ---------------- row softmax: S bf16 -> P bf16 -----------------------------
__global__ __launch_bounds__(256) void softmax_kernel(
    const ushort* __restrict__ S, ushort* __restrict__ P) {
  __shared__ float red[4];
  const int r = blockIdx.x, t = threadIdx.x, wid = t >> 6, lane = t & 63;
  const uint4* Sr = (const uint4*)(S + (size_t)r * NB);
  float v[16];
  float lmax = -1e30f;
#pragma unroll
  for (int i = 0; i < 2; ++i) {
    const uint4 c = Sr[t + 256 * i];
    const uint32_t w4[4] = {c.x, c.y, c.z, c.w};
#pragma unroll
    for (int j = 0; j < 4; ++j) {
      v[i * 8 + j * 2]     = bf2f((ushort)(w4[j] & 0xffffu));
      v[i * 8 + j * 2 + 1] = bf2f((ushort)(w4[j] >> 16));
    }
  }
#pragma unroll
  for (int u = 0; u < 16; ++u) lmax = fmaxf(lmax, v[u]);
  lmax = wave_reduce_max(lmax);
  if (lane == 0) red[wid] = lmax;
  __syncthreads();
  const float gmax = fmaxf(fmaxf(red[0], red[1]), fmaxf(red[2], red[3]));
  __syncthreads();
  float lsum = 0.f;
#pragma unroll
  for (int u = 0; u < 16; ++u) { v[u] = __expf(v[u] - gmax); lsum += v[u]; }
  lsum = wave_reduce_sum(lsum);
  if (lane == 0) red[wid] = lsum;
  __syncthreads();
  const float pinv = 1.f / (red[0] + red[1] + red[2] + red[3]);
  uint4* Pr = (uint4*)(P + (size_t)r * NB);
#pragma unroll
  for (int i = 0; i < 2; ++i) {
    uint4 o;
    o.x = (uint32_t)f2bf(v[i*8+0] * pinv) | ((uint32_t)f2bf(v[i*8+1] * pinv) << 16);
    o.y = (uint32_t)f2bf(v[i*8+2] * pinv) | ((uint32_t)f2bf(v[i*8+3] * pinv) << 16);
    o.z = (uint32_t)f2bf(v[i*8+4] * pinv) | ((uint32_t)f2bf(v[i*8+5] * pinv) << 16);
    o.w = (uint32_t)f2bf(v[i*8+6] * pinv) | ((uint32_t)f2bf(v[i*8+7] * pinv) << 16);
    Pr[t + 256 * i] = o;
  }
}

// ---------------- mega combine: both outputs --------------------------------
__global__ __launch_bounds__(256) void megacombine_kernel(
    const ushort* __restrict__ px, const ushort* __restrict__ ph,
    const float* __restrict__ t23, const ushort* __restrict__ xnb,
    const float* __restrict__ sv, const float* __restrict__ diag,
    const float* __restrict__ x, const float* __restrict__ h,
    const float* __restrict__ wvbT3, const float* __restrict__ mix,
    float* __restrict__ out_x, float* __restrict__ out_h) {
  __shared__ float rA[4], rB[4];
  const size_t NF = (size_t)NB * FD;
  const int i = blockIdx.x, f = threadIdx.x, wid = f >> 6, lane = f & 63;
  const float e0x = __expf(mix[0]), e1x = __expf(mix[2]);
  const float mAx = e0x / (e0x + e1x), mBx = e1x / (e0x + e1x);
  const float e0h = __expf(mix[1]), e1h = __expf(mix[3]);
  const float mAh = e0h / (e0h + e1h), mBh = e1h / (e0h + e1h);

  const size_t rowoff = (size_t)i * FD + f;
  float ax = 0.f, ah = 0.f;
#pragma unroll
  for (int z = 0; z < 4; ++z) {
    ax += bf2f(px[(size_t)z * NF + rowoff]);
    ah += bf2f(ph[(size_t)z * NF + rowoff]);
  }
  const float t2v = t23[(size_t)i * 512 + f];
  const float t3v = t23[(size_t)i * 512 + 256 + f];
  const float xv = bf2f(xnb[rowoff]);

  float rs = wave_reduce_sum(xv * sv[f]);
  float rq = wave_reduce_sum(xv * t2v);
  if (lane == 0) { rA[wid] = rs; rB[wid] = rq; }
  __syncthreads();
  rs = rA[0] + rA[1] + rA[2] + rA[3];
  rq = rB[0] + rB[1] + rB[2] + rB[3];
  const float mean = rs * (1.0f / NB);
  const float var = (rq - (float)NB * mean * mean) * (1.0f / (NB - 1));
  const float sd = sqrtf(fmaxf(var, 0.f));
  const float dg = diag[i];
  const float statsterm = dg * wvbT3[f] + rs * wvbT3[256 + f] + sd * wvbT3[512 + f];

  out_x[rowoff] = mBx * ax + mAx * t2v + x[rowoff];
  const float pre = mBh * ah + mAh * t3v + statsterm;
  out_h[rowoff] = ((pre > 0.f) ? pre : expm1f(pre)) + h[rowoff];
}

// ---------------- batched 64x64 BK=64 GEMM (3 slices) + colsum slice --------
struct GDesc {
  const ushort* A; const ushort* B; void* C;
  int lda, ldb, ldc, K, gx, gy, epi;   // epi: 1 bf16 store, 5 splitK fp32
  float alpha; long pstride; int nb;
};

__global__ __launch_bounds__(256) void gemm_batch4(
    GDesc d0, GDesc d1, GDesc d2,
    const ushort* __restrict__ xnT, float* __restrict__ sv, int ntot) {
  int flat = blockIdx.x;
  flat = (flat & 7) * (ntot >> 3) + (flat >> 3);   // XCD chunk swizzle
  const int ngemm = d0.nb + d1.nb + d2.nb;

  if (flat >= ngemm) {
    // ---- colsum slice: sv[f] = sum_i xn[i][f] (from xnT rows) ----
    __shared__ float red[4];
    const int f = flat - ngemm, t = threadIdx.x, wid = t >> 6, lane = t & 63;
    float a = 0.f;
#pragma unroll
    for (int i = 0; i < 16; ++i) a += bf2f(xnT[(size_t)f * NB + t + 256 * i]);
    a = wave_reduce_sum(a);
    if (lane == 0) red[wid] = a;
    __syncthreads();
    if (t == 0) sv[f] = red[0] + red[1] + red[2] + red[3];
    return;
  }

  GDesc d; int l;
  if (flat < d0.nb) { d = d0; l = flat; }
  else if (flat < d0.nb + d1.nb) { d = d1; l = flat - d0.nb; }
  else { d = d2; l = flat - d0.nb - d1.nb; }
  const int bx = l % d.gx;
  const int rest = l / d.gx;
  const int by = rest % d.gy, bz = rest / d.gy;

  __shared__ __align__(16) ushort At[2][64][64];
  __shared__ __align__(16) ushort Bt[2][64][64];
  const int tid = threadIdx.x;
  const int wave = tid >> 6, lane = tid & 63;
  const int wr = wave >> 1, wc = wave & 1;
  const int bi = by * 64, bj = bx * 64;
  const int fr = lane & 15, fq = lane >> 4;
  const int sub8 = lane >> 3, q8 = lane & 7;

  f32x4 acc[2][2];
#pragma unroll
  for (int m = 0; m < 2; ++m)
#pragma unroll
    for (int n = 0; n < 2; ++n) acc[m][n] = (f32x4){0.f, 0.f, 0.f, 0.f};

  const int kbase = bz * d.K;
  const int kend = kbase + d.K;

  // 64 rows of 64 bf16 = 128B rows; 3-bit chunk swizzle both sides.
  auto stage = [&](int bufi, int k0) {
    for (int c = wave; c < 8; c += 4) {
      const int row = c * 8 + sub8;
      const int qs = q8 ^ (row & 7);
      gld16(d.A + (size_t)(bi + row) * d.lda + k0 + qs * 8, &At[bufi][c * 8][0]);
    }
    for (int c = wave; c < 8; c += 4) {
      const int row = c * 8 + sub8;
      const int qs = q8 ^ (row & 7);
      gld16(d.B + (size_t)(bj + row) * d.ldb + k0 + qs * 8, &Bt[bufi][c * 8][0]);
    }
  };

  stage(0, kbase);
  __syncthreads();

  int cur = 0;
  for (int k0 = kbase; k0 < kend; k0 += 64) {
    if (k0 + 64 < kend) stage(cur ^ 1, k0 + 64);
#pragma unroll
    for (int ks = 0; ks < 2; ++ks) {
      bf16x8 a[2], b[2];
#pragma unroll
      for (int m = 0; m < 2; ++m) {
        const int row = wr * 32 + m * 16 + fr;
        const int ch = (ks * 4 + fq) ^ (row & 7);
        a[m] = *(const bf16x8*)((const char*)&At[cur][row][0] + ch * 16);
      }
#pragma unroll
      for (int n = 0; n < 2; ++n) {
        const int row = wc * 32 + n * 16 + fr;
        const int ch = (ks * 4 + fq) ^ (row & 7);
        b[n] = *(const bf16x8*)((const char*)&Bt[cur][row][0] + ch * 16);
      }
#pragma unroll
      for (int m = 0; m < 2; ++m)
#pragma unroll
        for (int n = 0; n < 2; ++n)
          acc[m][n] = __builtin_amdgcn_mfma_f32_16x16x32_bf16(a[m], b[n], acc[m][n], 0, 0, 0);
    }
    __syncthreads();
    cur ^= 1;
  }

#pragma unroll
  for (int m = 0; m < 2; ++m)
#pragma unroll
    for (int n = 0; n < 2; ++n)
#pragma unroll
      for (int r = 0; r < 4; ++r) {
        const int row = bi + wr * 32 + m * 16 + fq * 4 + r;
        const int col = bj + wc * 32 + n * 16 + fr;
        const size_t ci = (size_t)row * d.ldc + col;
        const float v = acc[m][n][r];
        if (d.epi == 1) ((ushort*)d.C)[ci] = f2bf(v * d.alpha);
        else ((float*)d.C)[(size_t)bz * d.pstride + ci] = v;
      }
}

// ---------------- 128x128 BK=64 core (shared by agg and batch2) -------------
#define GEMM128_BODY(APTR, BPTR, LDA, LDB, KBASE, KEND)                        \
  f32x4 acc[4][4];                                                             \
  _Pragma("unroll") for (int m = 0; m < 4; ++m)                                \
      _Pragma("unroll") for (int n = 0; n < 4; ++n)                            \
          acc[m][n] = (f32x4){0.f, 0.f, 0.f, 0.f};                             \
  auto stage = [&](int bufi, int k0) {                                         \
    for (int c = wave; c < 16; c += 4) {                                       \
      const int row = c * 8 + sub8;                                            \
      const int qs = q8 ^ (row & 7);                                           \
      gld16(APTR + (size_t)(bi + row) * LDA + k0 + qs * 8, &At[bufi][c * 8][0]); \
    }                                                                          \
    for (int c = wave; c < 16; c += 4) {                                       \
      const int row = c * 8 + sub8;                                            \
      const int qs = q8 ^ (row & 7);                                           \
      gld16(BPTR + (size_t)(bj + row) * LDB + k0 + qs * 8, &Bt[bufi][c * 8][0]); \
    }                                                                          \
  };                                                                           \
  stage(0, KBASE);                                                             \
  __syncthreads();                                                             \
  int cur = 0;                                                                 \
  for (int k0 = KBASE; k0 < KEND; k0 += 64) {                                  \
    if (k0 + 64 < KEND) stage(cur ^ 1, k0 + 64);                               \
    _Pragma("unroll") for (int ks = 0; ks < 2; ++ks) {                         \
      bf16x8 a[4], b[4];                                                       \
      _Pragma("unroll") for (int m = 0; m < 4; ++m) {                          \
        const int row = wr * 64 + m * 16 + fr;                                 \
        const int ch = (ks * 4 + fq) ^ (row & 7);                              \
        a[m] = *(const bf16x8*)((const char*)&At[cur][row][0] + ch * 16);      \
      }                                                                        \
      _Pragma("unroll") for (int n = 0; n < 4; ++n) {                          \
        const int row = wc * 64 + n * 16 + fr;                                 \
        const int ch = (ks * 4 + fq) ^ (row & 7);                              \
        b[n] = *(const bf16x8*)((const char*)&Bt[cur][row][0] + ch * 16);      \
      }                                                                        \
      _Pragma("unroll") for (int m = 0; m < 4; ++m)                            \
          _Pragma("unroll") for (int n = 0; n < 4; ++n)                        \
              acc[m][n] = __builtin_amdgcn_mfma_f32_16x16x32_bf16(             \
                  a[m], b[n], acc[m][n], 0, 0, 0);                             \
    }                                                                          \
    __syncthreads();                                                           \
    cur ^= 1;                                                                  \
  }

// ---------------- merged aggregation GEMM (BK=64): P@xnT and PT@hvT ---------
__global__ __launch_bounds__(256) void gemm_agg(
    const ushort* __restrict__ P, const ushort* __restrict__ PT,
    const ushort* __restrict__ xnT, const ushort* __restrict__ hvT,
    ushort* __restrict__ px, ushort* __restrict__ ph) {
  __shared__ __align__(16) ushort At[2][128][64];
  __shared__ __align__(16) ushort Bt[2][128][64];
  const int tid = threadIdx.x;
  const int wave = tid >> 6, lane = tid & 63;
  const int wr = wave >> 1, wc = wave & 1;

  const int nwg = 512;
  int flat = blockIdx.x + 2 * (blockIdx.y + 32 * blockIdx.z);
  flat = (flat & 7) * (nwg >> 3) + (flat >> 3);
  const int bx = flat % 2, by = (flat / 2) % 32, bz = flat / 64;
  const int sel = bz >> 2, kz = bz & 3;

  const ushort* A = sel ? PT : P;
  const ushort* B = sel ? hvT : xnT;
  ushort* C = sel ? ph : px;

  const int bi = by * 128, bj = bx * 128;
  const int fr = lane & 15, fq = lane >> 4;
  const int sub8 = lane >> 3, q8 = lane & 7;

  const int kbase = kz * 1024;
  const int kend = kbase + 1024;

  GEMM128_BODY(A, B, NB, NB, kbase, kend)

#pragma unroll
  for (int m = 0; m < 4; ++m)
#pragma unroll
    for (int n = 0; n < 4; ++n)
#pragma unroll
      for (int r = 0; r < 4; ++r) {
        const int row = bi + wr * 64 + m * 16 + fq * 4 + r;
        const int col = bj + wc * 64 + n * 16 + fr;
        C[(size_t)kz * ((size_t)NB * FD) + (size_t)row * FD + col] = f2bf(acc[m][n][r]);
      }
}

// ---------------- batched 128x128 BK=64 GEMM: S-GEMM + t23 ------------------
struct GD2 {
  const ushort* A; const ushort* B; void* C;
  int lda, ldb, ldc, K, gx, epi;   // epi: 0 fp32, 1 bf16*alpha
  float alpha; int nb;
};

__global__ __launch_bounds__(256) void gemm_batch2big(GD2 d0, GD2 d1, int ntot) {
  __shared__ __align__(16) ushort At[2][128][64];
  __shared__ __align__(16) ushort Bt[2][128][64];
  const int tid = threadIdx.x;
  const int wave = tid >> 6, lane = tid & 63;
  const int wr = wave >> 1, wc = wave & 1;

  int flat = blockIdx.x;
  flat = (flat & 7) * (ntot >> 3) + (flat >> 3);
  GD2 d; int l;
  if (flat < d0.nb) { d = d0; l = flat; }
  else { d = d1; l = flat - d0.nb; }
  const int bx = l % d.gx, by = l / d.gx;

  const int bi = by * 128, bj = bx * 128;
  const int fr = lane & 15, fq = lane >> 4;
  const int sub8 = lane >> 3, q8 = lane & 7;

  GEMM128_BODY(d.A, d.B, d.lda, d.ldb, 0, d.K)

#pragma unroll
  for (int m = 0; m < 4; ++m)
#pragma unroll
    for (int n = 0; n < 4; ++n)
#pragma unroll
      for (int r = 0; r < 4; ++r) {
        const int row = bi + wr * 64 + m * 16 + fq * 4 + r;
        const int col = bj + wc * 64 + n * 16 + fr;
        const size_t ci = (size_t)row * d.ldc + col;
        const float v = acc[m][n][r];
        if (d.epi == 1) ((ushort*)d.C)[ci] = f2bf(v * d.alpha);
        else ((float*)d.C)[ci] = v;
      }
}

// ---------------- NT bf16 MFMA GEMM (64² small, for Bv) ---------------------
template <int BM, int BN, int EPI>
__global__ __launch_bounds__(256) void gemm_nt(
    const ushort* __restrict__ A, int lda,
    const ushort* __restrict__ B, int ldb,
    void* __restrict__ Cp, int ldc, int K, float alpha,
    size_t pstride) {
  constexpr int WAVES_N = 2, WAVES_M = 2;
  constexpr int WM = BM / WAVES_M, WN = BN / WAVES_N;
  constexpr int MR = WM / 16, NR = WN / 16;
  __shared__ __align__(16) ushort At[2][BM][32];
  __shared__ __align__(16) ushort Bt[2][BN][32];
  const int tid = threadIdx.x;
  const int wave = tid >> 6, lane = tid & 63;
  const int wr = wave / WAVES_N, wc = wave % WAVES_N;

  const int bx = blockIdx.x, by = blockIdx.y;
  const int bi = by * BM, bj = bx * BN;
  const int fr = lane & 15, fq = lane >> 4;
  const int sub = lane >> 2, q = lane & 3;

  f32x4 acc[MR][NR];
#pragma unroll
  for (int m = 0; m < MR; ++m)
#pragma unroll
    for (int n = 0; n < NR; ++n) acc[m][n] = (f32x4){0.f, 0.f, 0.f, 0.f};

  auto stage = [&](int bufi, int k0) {
    for (int c = wave; c < BM / 16; c += 4) {
      const int row = c * 16 + sub;
      const int qs = q ^ (row & 3);
      gld16(A + (size_t)(bi + row) * lda + k0 + qs * 8, &At[bufi][c * 16][0]);
    }
    for (int c = wave; c < BN / 16; c += 4) {
      const int row = c * 16 + sub;
      const int qs = q ^ (row & 3);
      gld16(B + (size_t)(bj + row) * ldb + k0 + qs * 8, &Bt[bufi][c * 16][0]);
    }
  };

  stage(0, 0);
  __syncthreads();

  int cur = 0;
  for (int k0 = 0; k0 < K; k0 += 32) {
    if (k0 + 32 < K) stage(cur ^ 1, k0 + 32);
    bf16x8 a[MR], b[NR];
#pragma unroll
    for (int m = 0; m < MR; ++m) {
      const int row = wr * WM + m * 16 + fr;
      a[m] = *(const bf16x8*)((const char*)&At[cur][row][0] + ((fq ^ (row & 3)) * 16));
    }
#pragma unroll
    for (int n = 0; n < NR; ++n) {
      const int row = wc * WN + n * 16 + fr;
      b[n] = *(const bf16x8*)((const char*)&Bt[cur][row][0] + ((fq ^ (row & 3)) * 16));
    }
#pragma unroll
    for (int m = 0; m < MR; ++m)
#pragma unroll
      for (int n = 0; n < NR; ++n)
        acc[m][n] = __builtin_amdgcn_mfma_f32_16x16x32_bf16(a[m], b[n], acc[m][n], 0, 0, 0);
    __syncthreads();
    cur ^= 1;
  }

#pragma unroll
  for (int m = 0; m < MR; ++m)
#pragma unroll
    for (int n = 0; n < NR; ++n)
#pragma unroll
      for (int r = 0; r < 4; ++r) {
        const int row = bi + wr * WM + m * 16 + fq * 4 + r;
        const int col = bj + wc * WN + n * 16 + fr;
        const size_t ci = (size_t)row * ldc + col;
        const float v = acc[m][n][r];
        if (EPI == 0) ((float*)Cp)[ci] = v * alpha;
        else ((ushort*)Cp)[ci] = f2bf(v * alpha);
      }
}

// ---------------------------------------------------------------------------
extern "C" void kernel_launch(void* const* d_in, const int* in_sizes, int n_in,
                              void* d_out, int out_size, void* d_ws, size_t ws_size,
                              hipStream_t stream) {
  const float* h      = (const float*)d_in[0];
  const float* x      = (const float*)d_in[1];
  const float* w_k    = (const float*)d_in[2];
  const float* w_q    = (const float*)d_in[3];
  const float* w_v    = (const float*)d_in[4];
  const float* mixing = (const float*)d_in[5];
  const float* gamma  = (const float*)d_in[6];
  const float* beta   = (const float*)d_in[7];

  float* out_h = (float*)d_out;
  float* out_x = out_h + (size_t)NB * FD;

  char* w = (char*)d_ws;
  ushort* S     = (ushort*)(w + 0);           // 32MB bf16 scores
  ushort* P     = (ushort*)(w + 33554432);    // 32MB
  ushort* PT    = (ushort*)(w + 67108864);    // 32MB
  ushort* hnb   = (ushort*)(w + 100663296);   // 2MB
  ushort* xnb   = (ushort*)(w + 102760448);   // 2MB
  ushort* xnbT  = (ushort*)(w + 104857600);   // 2MB  [256][NB]
  ushort* hnbT  = (ushort*)(w + 106954752);   // 2MB  [256][NB]
  ushort* kq    = (ushort*)(w + 109051904);   // 4MB  [NB][512]
  ushort* hvT   = (ushort*)(w + 113246208);   // 2MB  [256][NB]
  float*  t23   = (float*)(w + 115343360);    // 8MB  [NB][512]
  ushort* t23B  = (ushort*)(w + 123731968);   // 256KB [512][256] (G | Bv)
  ushort* M2T   = (ushort*)(w + 123994112);   // 128KB
  ushort* wkqb  = (ushort*)(w + 124125184);   // 256KB [512][256]
  ushort* wvAb  = (ushort*)(w + 124387328);   // 128KB
  float*  wvbT3 = (float*)(w + 124518400);    // 3KB
  float*  diag  = (float*)(w + 124521472);    // 16KB
  float*  sv    = (float*)(w + 124537856);    // 1KB
  // aliases (disjoint lifetimes):
  float*  Gramp = (float*)(w + 67108864);     // 8MB in PT region (dead before PT)
  ushort* px    = (ushort*)(w + 0);           // 8MB in S region (S dead after softmax)
  ushort* ph    = (ushort*)(w + 16777216);    // 8MB

  rownorm_wcast_kernel<<<NB + FD, 256, 0, stream>>>(
      h, x, gamma, beta, hnb, xnb, diag, w_k, w_q, w_v, wkqb, wvAb, wvbT3);
  transpose2_kernel<<<dim3(FD / 64, NB / 64, 2), 256, 0, stream>>>(
      xnb, xnbT, hnb, hnbT, NB, FD);

  // batched: kq | Gram stacked (split-K 16) | hvT | colsum (1536 blocks)
  {
    GDesc dkq = {hnb, wkqb, kq, FD, FD, 512, FD, 8, 64, 1, 1.f, 0, 512};
    GDesc dgr = {xnbT, xnbT, Gramp, NB, NB, 512, NB / 16, 8, 4, 5, 1.f,
                 (long)(256 * 512), 512};
    GDesc dhv = {wvAb, hnb, hvT, FD, FD, NB, FD, 64, 4, 1, 1.f, 0, 256};
    gemm_batch4<<<1536, 256, 0, stream>>>(dkq, dgr, dhv, xnbT, sv, 1536);
  }
  reduce16g_kernel<<<256 * 512 / 256, 256, 0, stream>>>(Gramp, t23B, M2T);

  // Bv = w_vA @ M2 (via M2T)
  gemm_nt<64, 64, 1><<<dim3(4, 4), 256, 0, stream>>>(
      wvAb, FD, M2T, FD, t23B + 256 * 256, FD, FD, 1.f, 0);

  // batched big: S = bf16((k@q^T)/16) | t23 = xn @ [G; Bv]^T (fp32)
  {
    GD2 dS  = {kq, kq + 256, S, 512, 512, NB, FD, 32, 1, 0.0625f, 1024};
    GD2 dT  = {xnb, t23B, t23, FD, FD, 512, FD, 4, 0, 1.f, 128};
    gemm_batch2big<<<1152, 256, 0, stream>>>(dS, dT, 1152);
  }

  // softmax: S -> P ; vectorized transpose: P -> PT
  softmax_kernel<<<NB, 256, 0, stream>>>(S, P);
  transpose4_kernel<<<dim3(NB / 64, NB / 64), 256, 0, stream>>>(P, PT, NB, NB);

  // merged aggregation partials: 128x128 tiles BK=64, split-K 4, both GEMMs
  gemm_agg<<<dim3(2, 32, 8), 256, 0, stream>>>(P, PT, xnbT, hvT, px, ph);

  // mega combine -> out_x, out_h
  megacombine_kernel<<<NB, 256, 0, stream>>>(
      px, ph, t23, xnb, sv, diag, x, h, wvbT3, mixing, out_x, out_h);
}